// Round 1
// baseline (734.864 us; speedup 1.0000x reference)
//
#include <hip/hip_runtime.h>
#include <cmath>

#define BATCH 4
#define CH    512
#define HCH   256
#define NPIX  4096
#define L2E   1.44269504088896340736f

typedef __attribute__((ext_vector_type(8))) short bf16x8;
typedef __attribute__((ext_vector_type(4))) float f32x4;

#define MFMA16(a, b, c) __builtin_amdgcn_mfma_f32_16x16x32_bf16((a), (b), (c), 0, 0, 0)

__device__ __forceinline__ unsigned short f2bf(float f) {
    unsigned int u = __float_as_uint(f);
    return (unsigned short)((u + 0x7fffu + ((u >> 16) & 1u)) >> 16);
}
__device__ __forceinline__ ushort4 pack4(float a, float b, float c, float d) {
    ushort4 u; u.x = f2bf(a); u.y = f2bf(b); u.z = f2bf(c); u.w = f2bf(d); return u;
}

// ---------------------------------------------------------------------------
// Wc[1024][512] bf16 = concat(Wf, Wg, Wh) rows, K-contiguous.
// ---------------------------------------------------------------------------
__global__ __launch_bounds__(256) void convert_w_kernel(
    const float* __restrict__ Wf, const float* __restrict__ Wg,
    const float* __restrict__ Wh, unsigned short* __restrict__ Wc)
{
    const int idx = blockIdx.x * 256 + threadIdx.x;
    const int o  = idx >> 7;
    const int c4 = (idx & 127) * 4;
    const float* src = (o < HCH)     ? (Wf + (size_t)o * CH + c4)
                     : (o < 2 * HCH) ? (Wg + (size_t)(o - HCH) * CH + c4)
                                     : (Wh + (size_t)(o - 2 * HCH) * CH + c4);
    float4 v = *(const float4*)src;
    *(ushort4*)&Wc[(size_t)o * CH + c4] = pack4(v.x, v.y, v.z, v.w);
}

// ---------------------------------------------------------------------------
// X' swizzle: x fp32 [b][512][4096] -> bf16 [b][cb=16][n=4096][co=32].
// ---------------------------------------------------------------------------
__global__ __launch_bounds__(256) void convert_x_kernel(
    const float* __restrict__ x, unsigned short* __restrict__ Xp)
{
    __shared__ unsigned short Lt[64][40];
    const int b  = blockIdx.z;
    const int cb = blockIdx.y;
    const int n0 = blockIdx.x * 64;
    const int t  = threadIdx.x;
    const int cr = t >> 4;
    const int f4 = t & 15;
    #pragma unroll
    for (int p = 0; p < 2; ++p) {
        const int c = p * 16 + cr;
        float4 v = *(const float4*)(x + ((size_t)b * CH + cb * 32 + c) * NPIX + n0 + f4 * 4);
        Lt[f4 * 4 + 0][c] = f2bf(v.x);
        Lt[f4 * 4 + 1][c] = f2bf(v.y);
        Lt[f4 * 4 + 2][c] = f2bf(v.z);
        Lt[f4 * 4 + 3][c] = f2bf(v.w);
    }
    __syncthreads();
    const int n  = t >> 2;
    const int ch = t & 3;
    uint4 u = *(const uint4*)&Lt[n][ch * 8];
    *(uint4*)&Xp[((size_t)b * 16 + cb) * (NPIX * 32) + (size_t)(n0 + n) * 32 + ch * 8] = u;
}

// ---------------------------------------------------------------------------
// proj F/G (unchanged)
// ---------------------------------------------------------------------------
__global__ __launch_bounds__(256, 2) void proj_fg_kernel(
    const unsigned short* __restrict__ Wc, const unsigned short* __restrict__ Xp,
    const float* __restrict__ bf, const float* __restrict__ bg,
    unsigned short* __restrict__ F, unsigned short* __restrict__ G)
{
    const int b  = blockIdx.z;
    const int n0 = blockIdx.x * 128;
    const int o0 = blockIdx.y * 128;
    const int t  = threadIdx.x;
    const int wave = t >> 6, lane = t & 63, quad = lane >> 4, l16 = lane & 15;
    const int ow = o0 + wave * 32;

    f32x4 acc[2][8];
    #pragma unroll
    for (int ms = 0; ms < 2; ++ms)
        #pragma unroll
        for (int ns = 0; ns < 8; ++ns) acc[ms][ns] = (f32x4){0.f, 0.f, 0.f, 0.f};

    const unsigned short* xb = Xp + (size_t)b * 16 * (NPIX * 32);
    for (int st = 0; st < 16; ++st) {
        bf16x8 a0 = *(const bf16x8*)&Wc[(size_t)(ow + l16) * CH + st * 32 + quad * 8];
        bf16x8 a1 = *(const bf16x8*)&Wc[(size_t)(ow + 16 + l16) * CH + st * 32 + quad * 8];
        const unsigned short* xs = xb + (size_t)st * (NPIX * 32) + quad * 8;
        #pragma unroll
        for (int ns = 0; ns < 8; ++ns) {
            bf16x8 bb = *(const bf16x8*)(xs + (size_t)(n0 + ns * 16 + l16) * 32);
            acc[0][ns] = MFMA16(a0, bb, acc[0][ns]);
            acc[1][ns] = MFMA16(a1, bb, acc[1][ns]);
        }
    }

    const int orow = quad * 4;
    #pragma unroll
    for (int ms = 0; ms < 2; ++ms) {
        const int ob = ow + ms * 16 + orow;
        float bias[4];
        #pragma unroll
        for (int r = 0; r < 4; ++r)
            bias[r] = (o0 < HCH) ? bf[ob + r] : bg[ob + r - HCH];
        #pragma unroll
        for (int ns = 0; ns < 8; ++ns) {
            const int n = n0 + ns * 16 + l16;
            ushort4 u = pack4(acc[ms][ns][0] + bias[0], acc[ms][ns][1] + bias[1],
                              acc[ms][ns][2] + bias[2], acc[ms][ns][3] + bias[3]);
            if (o0 < HCH) {
                *(ushort4*)&F[((size_t)b * NPIX + n) * HCH + ob] = u;
            } else {
                const int og = ob - HCH;
                const int cb = og >> 5, co = og & 31;
                *(ushort4*)&G[((size_t)b * 8 + cb) * (NPIX * 32) + (size_t)n * 32 + co] = u;
            }
        }
    }
}

// ---------------------------------------------------------------------------
// proj V (unchanged)
// ---------------------------------------------------------------------------
__global__ __launch_bounds__(256, 2) void proj_v_kernel(
    const unsigned short* __restrict__ Wc, const unsigned short* __restrict__ Xp,
    const float* __restrict__ bh, unsigned short* __restrict__ V)
{
    const int b  = blockIdx.z;
    const int c0 = blockIdx.x * 128;
    const int p0 = blockIdx.y * 128;
    const int t  = threadIdx.x;
    const int wave = t >> 6, lane = t & 63, quad = lane >> 4, l16 = lane & 15;
    const int pw = p0 + wave * 32;

    f32x4 acc[2][8];
    #pragma unroll
    for (int ms = 0; ms < 2; ++ms)
        #pragma unroll
        for (int ns = 0; ns < 8; ++ns) acc[ms][ns] = (f32x4){0.f, 0.f, 0.f, 0.f};

    const unsigned short* xb = Xp + (size_t)b * 16 * (NPIX * 32);
    for (int st = 0; st < 16; ++st) {
        const unsigned short* xs = xb + (size_t)st * (NPIX * 32) + quad * 8;
        bf16x8 a0 = *(const bf16x8*)(xs + (size_t)(pw + l16) * 32);
        bf16x8 a1 = *(const bf16x8*)(xs + (size_t)(pw + 16 + l16) * 32);
        #pragma unroll
        for (int ns = 0; ns < 8; ++ns) {
            bf16x8 bb = *(const bf16x8*)&Wc[(size_t)(2 * HCH + c0 + ns * 16 + l16) * CH + st * 32 + quad * 8];
            acc[0][ns] = MFMA16(a0, bb, acc[0][ns]);
            acc[1][ns] = MFMA16(a1, bb, acc[1][ns]);
        }
    }

    float biasv[8];
    #pragma unroll
    for (int ns = 0; ns < 8; ++ns) biasv[ns] = bh[c0 + ns * 16 + l16];

    const int kb = pw >> 5;
    const int ko0 = quad * 4;
    #pragma unroll
    for (int ms = 0; ms < 2; ++ms) {
        #pragma unroll
        for (int ns = 0; ns < 8; ++ns) {
            const int c = c0 + ns * 16 + l16;
            ushort4 u = pack4(acc[ms][ns][0] + biasv[ns], acc[ms][ns][1] + biasv[ns],
                              acc[ms][ns][2] + biasv[ns], acc[ms][ns][3] + biasv[ns]);
            *(ushort4*)&V[((size_t)b * 128 + kb) * (CH * 32) + (size_t)c * 32 + ms * 16 + ko0] = u;
        }
    }
}

// ---------------------------------------------------------------------------
// Stats: 64q, 512 thr, k-half split -> grid 512 (2 blocks/CU).
// waves_per_eu(4,4): cap 128 VGPR so af[2][8] (64 VGPR) stays RESIDENT
// (at the old 64-VGPR choice the compiler re-loaded F from L2 every k-tile).
// ---------------------------------------------------------------------------
__global__ void __launch_bounds__(512) __attribute__((amdgpu_waves_per_eu(4, 4)))
stats_kernel(
    const unsigned short* __restrict__ F, const unsigned short* __restrict__ G,
    float* __restrict__ rowl)
{
    const int blk = blockIdx.x;
    const int xcd = blk & 7;
    const int b   = xcd >> 1;
    const int kh  = xcd & 1;
    const int q0  = (blk >> 3) * 64;
    const int t    = threadIdx.x;
    const int wave = t >> 6, lane = t & 63, quad = lane >> 4, l16 = lane & 15;
    const int qh = wave >> 2, kw = wave & 3;

    bf16x8 af[2][8];
    #pragma unroll
    for (int qs = 0; qs < 2; ++qs)
        #pragma unroll
        for (int st = 0; st < 8; ++st)
            af[qs][st] = *(const bf16x8*)&F[((size_t)b * NPIX + q0 + qh * 32 + qs * 16 + l16) * HCH + st * 32 + quad * 8];

    float ls[2][4];
    #pragma unroll
    for (int qs = 0; qs < 2; ++qs)
        #pragma unroll
        for (int r = 0; r < 4; ++r) ls[qs][r] = 0.f;

    const unsigned short* Gb = G + (size_t)b * 8 * (NPIX * 32);
    const int kbeg = kh * 2048, kend = kbeg + 2048;
    for (int k0 = kbeg; k0 < kend; k0 += 128) {
        const int kk = k0 + kw * 32;
        f32x4 s[2][2];
        #pragma unroll
        for (int qs = 0; qs < 2; ++qs)
            #pragma unroll
            for (int ks = 0; ks < 2; ++ks) s[qs][ks] = (f32x4){0.f, 0.f, 0.f, 0.f};
        #pragma unroll
        for (int st = 0; st < 8; ++st) {
            const unsigned short* gs = Gb + (size_t)st * (NPIX * 32) + quad * 8;
            bf16x8 b0 = *(const bf16x8*)(gs + (size_t)(kk + l16) * 32);
            bf16x8 b1 = *(const bf16x8*)(gs + (size_t)(kk + 16 + l16) * 32);
            s[0][0] = MFMA16(af[0][st], b0, s[0][0]);
            s[1][0] = MFMA16(af[1][st], b0, s[1][0]);
            s[0][1] = MFMA16(af[0][st], b1, s[0][1]);
            s[1][1] = MFMA16(af[1][st], b1, s[1][1]);
        }
        #pragma unroll
        for (int qs = 0; qs < 2; ++qs)
            #pragma unroll
            for (int r = 0; r < 4; ++r)
                ls[qs][r] += exp2f(L2E * s[qs][0][r]) + exp2f(L2E * s[qs][1][r]);
    }

    #pragma unroll
    for (int d = 1; d < 16; d <<= 1)
        #pragma unroll
        for (int qs = 0; qs < 2; ++qs)
            #pragma unroll
            for (int r = 0; r < 4; ++r) ls[qs][r] += __shfl_xor(ls[qs][r], d, 64);

    if (l16 == 0) {
        #pragma unroll
        for (int qs = 0; qs < 2; ++qs)
            #pragma unroll
            for (int r = 0; r < 4; ++r)
                atomicAdd(&rowl[(size_t)b * NPIX + q0 + qh * 32 + qs * 16 + quad * 4 + r], ls[qs][r]);
    }
}

// ---------------------------------------------------------------------------
// Apply: 64q x 256c-half per block, 512 thr, grid 512 (2 blocks/CU).
// Changes vs previous version:
//  - F tile (64x256, 32KB) staged once into LDS, XOR-swizzled
//    (byte ^= (row&7)<<4) -> conflict-free ds_read_b128; frees the 64-VGPR
//    persistent af[] that previously forced per-tile F re-loads from L2.
//  - P un-padded to [2][64][128] (32KB) with the same XOR swizzle
//    (Fs+P = exactly 64KB static LDS, still 2 blocks/CU).
//  - waves_per_eu(4,4): allow up to 128 VGPR (grid-limited to 4 waves/EU
//    anyway) so the scheduler can hoist G loads.
//  - V tile prefetched into vreg[4][2] one k-tile ahead: loads stay in
//    flight across the barrier and are covered by the next QK phase.
// ---------------------------------------------------------------------------
__global__ void __launch_bounds__(512) __attribute__((amdgpu_waves_per_eu(4, 4)))
apply_kernel(
    const unsigned short* __restrict__ F, const unsigned short* __restrict__ G,
    const unsigned short* __restrict__ V, const float* __restrict__ rowl,
    float* __restrict__ outres, float* __restrict__ attnacc)
{
    __shared__ unsigned short Fs[64 * 256];     // 32 KB, XOR-swizzled
    __shared__ unsigned short P[2][64][128];    // 32 KB, XOR-swizzled
    const int blk = blockIdx.x;
    const int xcd = blk & 7;
    const int b   = xcd >> 1;
    const int ch  = xcd & 1;
    const int q0  = (blk >> 3) * 64;
    const int t    = threadIdx.x;
    const int wave = t >> 6, lane = t & 63, quad = lane >> 4, l16 = lane & 15;
    const int qh = wave >> 2, kw = wave & 3;
    const int cw = ch * 256 + wave * 32;    // wave's 32-c strip

    // ---- stage F tile into LDS (once). row stride 512B; XOR (row&7)<<4.
    #pragma unroll
    for (int j = 0; j < 4; ++j) {
        const int idx   = j * 512 + t;       // 16B-chunk id, 0..2047
        const int row   = idx >> 5;          // 0..63
        const int chunk = idx & 31;          // 0..31
        bf16x8 v = *(const bf16x8*)&F[((size_t)b * NPIX + q0 + row) * HCH + chunk * 8];
        const int byte = (row * 512 + chunk * 16) ^ ((row & 7) << 4);
        *(bf16x8*)((char*)Fs + byte) = v;
    }

    float linv[2][4];
    #pragma unroll
    for (int qs = 0; qs < 2; ++qs)
        #pragma unroll
        for (int r = 0; r < 4; ++r)
            linv[qs][r] = 1.0f / rowl[(size_t)b * NPIX + q0 + qh * 32 + qs * 16 + quad * 4 + r];

    f32x4 O[4][2];
    #pragma unroll
    for (int qs = 0; qs < 4; ++qs)
        #pragma unroll
        for (int ct = 0; ct < 2; ++ct) O[qs][ct] = (f32x4){0.f, 0.f, 0.f, 0.f};

    const unsigned short* Gb = G + (size_t)b * 8 * (NPIX * 32);
    const unsigned short* Vb = V + (size_t)b * 128 * (CH * 32);

    // ---- V prefetch for tile 0 (independent of LDS; issued before barrier)
    bf16x8 vreg[4][2];
    {
        const unsigned short* vs = Vb + quad * 8;
        #pragma unroll
        for (int ks = 0; ks < 4; ++ks)
            #pragma unroll
            for (int ct = 0; ct < 2; ++ct)
                vreg[ks][ct] = *(const bf16x8*)(vs + (size_t)ks * (CH * 32) + (size_t)(cw + ct * 16 + l16) * 32);
    }

    __syncthreads();   // Fs staged

    // per-thread Fs read bases: row = qh*32 + qs*16 + l16
    const int fx = (l16 & 7) << 4;
    const int fbase0 = (qh * 32 + l16) * 512 + quad * 16;
    const int fbase1 = (qh * 32 + 16 + l16) * 512 + quad * 16;

    int buf = 0;
    for (int k0 = 0; k0 < NPIX; k0 += 128) {
        const int kk = k0 + kw * 32;
        f32x4 s[2][2];
        #pragma unroll
        for (int qs = 0; qs < 2; ++qs)
            #pragma unroll
            for (int ks = 0; ks < 2; ++ks) s[qs][ks] = (f32x4){0.f, 0.f, 0.f, 0.f};

        #pragma unroll
        for (int st = 0; st < 8; ++st) {
            const unsigned short* gs = Gb + (size_t)st * (NPIX * 32) + quad * 8;
            bf16x8 b0 = *(const bf16x8*)(gs + (size_t)(kk + l16) * 32);
            bf16x8 b1 = *(const bf16x8*)(gs + (size_t)(kk + 16 + l16) * 32);
            bf16x8 a0 = *(const bf16x8*)((const char*)Fs + ((fbase0 + st * 64) ^ fx));
            bf16x8 a1 = *(const bf16x8*)((const char*)Fs + ((fbase1 + st * 64) ^ fx));
            s[0][0] = MFMA16(a0, b0, s[0][0]);
            s[1][0] = MFMA16(a1, b0, s[1][0]);
            s[0][1] = MFMA16(a0, b1, s[0][1]);
            s[1][1] = MFMA16(a1, b1, s[1][1]);
        }

        float p[2][2][4];
        #pragma unroll
        for (int qs = 0; qs < 2; ++qs)
            #pragma unroll
            for (int ks = 0; ks < 2; ++ks)
                #pragma unroll
                for (int r = 0; r < 4; ++r)
                    p[qs][ks][r] = exp2f(L2E * s[qs][ks][r]) * linv[qs][r];

        // P writes, XOR-swizzled: byte = (row*256 + col*2) ^ ((row&7)<<4)
        {
            char* Pb = (char*)&P[buf][0][0];
            #pragma unroll
            for (int qs = 0; qs < 2; ++qs)
                #pragma unroll
                for (int ks = 0; ks < 2; ++ks)
                    #pragma unroll
                    for (int r = 0; r < 4; ++r) {
                        const int row = qh * 32 + qs * 16 + quad * 4 + r;
                        const int col = kw * 32 + ks * 16 + l16;
                        const int byte = (row * 256 + col * 2) ^ ((row & 7) << 4);
                        *(unsigned short*)(Pb + byte) = f2bf(p[qs][ks][r]);
                    }
        }

        if (ch == 0) {
            #pragma unroll
            for (int ks = 0; ks < 2; ++ks) {
                float cs = p[0][ks][0] + p[0][ks][1] + p[0][ks][2] + p[0][ks][3]
                         + p[1][ks][0] + p[1][ks][1] + p[1][ks][2] + p[1][ks][3];
                cs += __shfl_xor(cs, 16, 64);
                cs += __shfl_xor(cs, 32, 64);
                if (quad == 0)
                    atomicAdd(&attnacc[(size_t)b * NPIX + kk + ks * 16 + l16], cs);
            }
        }

        __syncthreads();   // P[buf] complete; t+1 writes go to buf^1 (race-free)

        // PV from LDS P (XOR-swizzled read, conflict-free) x registered V
        {
            const char* Pb = (const char*)&P[buf][0][0];
            #pragma unroll
            for (int ks = 0; ks < 4; ++ks) {
                bf16x8 pa[4];
                #pragma unroll
                for (int qs = 0; qs < 4; ++qs) {
                    const int row = qs * 16 + l16;
                    const int byte = (row * 256 + ks * 64 + quad * 16) ^ ((row & 7) << 4);
                    pa[qs] = *(const bf16x8*)(Pb + byte);
                }
                #pragma unroll
                for (int ct = 0; ct < 2; ++ct)
                    #pragma unroll
                    for (int qs = 0; qs < 4; ++qs)
                        O[qs][ct] = MFMA16(pa[qs], vreg[ks][ct], O[qs][ct]);
            }
        }

        // prefetch V for next tile: in flight across barrier + next QK phase
        if (k0 + 128 < NPIX) {
            const unsigned short* vs = Vb + (size_t)((k0 + 128) >> 5) * (CH * 32) + quad * 8;
            #pragma unroll
            for (int ks = 0; ks < 4; ++ks)
                #pragma unroll
                for (int ct = 0; ct < 2; ++ct)
                    vreg[ks][ct] = *(const bf16x8*)(vs + (size_t)ks * (CH * 32) + (size_t)(cw + ct * 16 + l16) * 32);
        }
        buf ^= 1;
    }

    #pragma unroll
    for (int qs = 0; qs < 4; ++qs) {
        #pragma unroll
        for (int ct = 0; ct < 2; ++ct) {
            const int c = cw + ct * 16 + l16;
            *(f32x4*)&outres[((size_t)b * CH + c) * NPIX + q0 + qs * 16 + quad * 4] = O[qs][ct];
        }
    }
}

__global__ __launch_bounds__(256) void attn_fin_kernel(
    const float* __restrict__ acc, float* __restrict__ outa)
{
    const int i = blockIdx.x * 256 + threadIdx.x;
    if (i < BATCH * NPIX) outa[i] = acc[i] * (1.0f / (float)NPIX);
}

extern "C" void kernel_launch(void* const* d_in, const int* in_sizes, int n_in,
                              void* d_out, int out_size, void* d_ws, size_t ws_size,
                              hipStream_t stream)
{
    (void)in_sizes; (void)n_in; (void)out_size; (void)ws_size;
    const float* x  = (const float*)d_in[0];
    const float* Wf = (const float*)d_in[1];
    const float* bf = (const float*)d_in[2];
    const float* Wg = (const float*)d_in[3];
    const float* bg = (const float*)d_in[4];
    const float* Wh = (const float*)d_in[5];
    const float* bh = (const float*)d_in[6];
    float* out = (float*)d_out;

    unsigned short* Xp = (unsigned short*)d_ws;                      // 4*16*4096*32
    unsigned short* Wc = Xp + (size_t)BATCH * 16 * NPIX * 32;        // 1024*512
    unsigned short* F  = Wc + (size_t)1024 * CH;                     // 4*4096*256
    unsigned short* G  = F + (size_t)BATCH * NPIX * HCH;             // 4*8*4096*32
    unsigned short* V  = G + (size_t)BATCH * NPIX * HCH;             // 4*128*512*32
    float* rowl    = (float*)(V + (size_t)BATCH * NPIX * CH);        // 4*4096
    float* attnacc = rowl + (size_t)BATCH * NPIX;                    // 4*4096

    hipMemsetAsync(rowl, 0, (size_t)2 * BATCH * NPIX * sizeof(float), stream);

    convert_w_kernel<<<512, 256, 0, stream>>>(Wf, Wg, Wh, Wc);
    convert_x_kernel<<<dim3(NPIX / 64, 16, BATCH), 256, 0, stream>>>(x, Xp);

    proj_fg_kernel<<<dim3(NPIX / 128, 4, BATCH), 256, 0, stream>>>(Wc, Xp, bf, bg, F, G);
    proj_v_kernel<<<dim3(4, NPIX / 128, BATCH), 256, 0, stream>>>(Wc, Xp, bh, V);

    stats_kernel<<<512, 512, 0, stream>>>(F, G, rowl);
    apply_kernel<<<512, 512, 0, stream>>>(F, G, V, rowl, out, attnacc);

    attn_fin_kernel<<<BATCH * NPIX / 256, 256, 0, stream>>>(
        attnacc, out + (size_t)BATCH * CH * NPIX);
}

// Round 2
// 554.721 us; speedup vs baseline: 1.3247x; 1.3247x over previous
//
#include <hip/hip_runtime.h>
#include <cmath>

#define BATCH 4
#define CH    512
#define HCH   256
#define NPIX  4096
#define L2E   1.44269504088896340736f

typedef __attribute__((ext_vector_type(8))) short bf16x8;
typedef __attribute__((ext_vector_type(4))) float f32x4;

#define MFMA16(a, b, c) __builtin_amdgcn_mfma_f32_16x16x32_bf16((a), (b), (c), 0, 0, 0)

__device__ __forceinline__ unsigned short f2bf(float f) {
    unsigned int u = __float_as_uint(f);
    return (unsigned short)((u + 0x7fffu + ((u >> 16) & 1u)) >> 16);
}
__device__ __forceinline__ ushort4 pack4(float a, float b, float c, float d) {
    ushort4 u; u.x = f2bf(a); u.y = f2bf(b); u.z = f2bf(c); u.w = f2bf(d); return u;
}

// ---------------------------------------------------------------------------
// Wc[1024][512] bf16 = concat(Wf, Wg, Wh) rows, K-contiguous.
// ---------------------------------------------------------------------------
__global__ __launch_bounds__(256) void convert_w_kernel(
    const float* __restrict__ Wf, const float* __restrict__ Wg,
    const float* __restrict__ Wh, unsigned short* __restrict__ Wc)
{
    const int idx = blockIdx.x * 256 + threadIdx.x;
    const int o  = idx >> 7;
    const int c4 = (idx & 127) * 4;
    const float* src = (o < HCH)     ? (Wf + (size_t)o * CH + c4)
                     : (o < 2 * HCH) ? (Wg + (size_t)(o - HCH) * CH + c4)
                                     : (Wh + (size_t)(o - 2 * HCH) * CH + c4);
    float4 v = *(const float4*)src;
    *(ushort4*)&Wc[(size_t)o * CH + c4] = pack4(v.x, v.y, v.z, v.w);
}

// ---------------------------------------------------------------------------
// X' swizzle: x fp32 [b][512][4096] -> bf16 [b][cb=16][n=4096][co=32].
// ---------------------------------------------------------------------------
__global__ __launch_bounds__(256) void convert_x_kernel(
    const float* __restrict__ x, unsigned short* __restrict__ Xp)
{
    __shared__ unsigned short Lt[64][40];
    const int b  = blockIdx.z;
    const int cb = blockIdx.y;
    const int n0 = blockIdx.x * 64;
    const int t  = threadIdx.x;
    const int cr = t >> 4;
    const int f4 = t & 15;
    #pragma unroll
    for (int p = 0; p < 2; ++p) {
        const int c = p * 16 + cr;
        float4 v = *(const float4*)(x + ((size_t)b * CH + cb * 32 + c) * NPIX + n0 + f4 * 4);
        Lt[f4 * 4 + 0][c] = f2bf(v.x);
        Lt[f4 * 4 + 1][c] = f2bf(v.y);
        Lt[f4 * 4 + 2][c] = f2bf(v.z);
        Lt[f4 * 4 + 3][c] = f2bf(v.w);
    }
    __syncthreads();
    const int n  = t >> 2;
    const int ch = t & 3;
    uint4 u = *(const uint4*)&Lt[n][ch * 8];
    *(uint4*)&Xp[((size_t)b * 16 + cb) * (NPIX * 32) + (size_t)(n0 + n) * 32 + ch * 8] = u;
}

// ---------------------------------------------------------------------------
// proj F/G (round-0, unchanged)
// ---------------------------------------------------------------------------
__global__ __launch_bounds__(256, 2) void proj_fg_kernel(
    const unsigned short* __restrict__ Wc, const unsigned short* __restrict__ Xp,
    const float* __restrict__ bf, const float* __restrict__ bg,
    unsigned short* __restrict__ F, unsigned short* __restrict__ G)
{
    const int b  = blockIdx.z;
    const int n0 = blockIdx.x * 128;
    const int o0 = blockIdx.y * 128;
    const int t  = threadIdx.x;
    const int wave = t >> 6, lane = t & 63, quad = lane >> 4, l16 = lane & 15;
    const int ow = o0 + wave * 32;

    f32x4 acc[2][8];
    #pragma unroll
    for (int ms = 0; ms < 2; ++ms)
        #pragma unroll
        for (int ns = 0; ns < 8; ++ns) acc[ms][ns] = (f32x4){0.f, 0.f, 0.f, 0.f};

    const unsigned short* xb = Xp + (size_t)b * 16 * (NPIX * 32);
    for (int st = 0; st < 16; ++st) {
        bf16x8 a0 = *(const bf16x8*)&Wc[(size_t)(ow + l16) * CH + st * 32 + quad * 8];
        bf16x8 a1 = *(const bf16x8*)&Wc[(size_t)(ow + 16 + l16) * CH + st * 32 + quad * 8];
        const unsigned short* xs = xb + (size_t)st * (NPIX * 32) + quad * 8;
        #pragma unroll
        for (int ns = 0; ns < 8; ++ns) {
            bf16x8 bb = *(const bf16x8*)(xs + (size_t)(n0 + ns * 16 + l16) * 32);
            acc[0][ns] = MFMA16(a0, bb, acc[0][ns]);
            acc[1][ns] = MFMA16(a1, bb, acc[1][ns]);
        }
    }

    const int orow = quad * 4;
    #pragma unroll
    for (int ms = 0; ms < 2; ++ms) {
        const int ob = ow + ms * 16 + orow;
        float bias[4];
        #pragma unroll
        for (int r = 0; r < 4; ++r)
            bias[r] = (o0 < HCH) ? bf[ob + r] : bg[ob + r - HCH];
        #pragma unroll
        for (int ns = 0; ns < 8; ++ns) {
            const int n = n0 + ns * 16 + l16;
            ushort4 u = pack4(acc[ms][ns][0] + bias[0], acc[ms][ns][1] + bias[1],
                              acc[ms][ns][2] + bias[2], acc[ms][ns][3] + bias[3]);
            if (o0 < HCH) {
                *(ushort4*)&F[((size_t)b * NPIX + n) * HCH + ob] = u;
            } else {
                const int og = ob - HCH;
                const int cb = og >> 5, co = og & 31;
                *(ushort4*)&G[((size_t)b * 8 + cb) * (NPIX * 32) + (size_t)n * 32 + co] = u;
            }
        }
    }
}

// ---------------------------------------------------------------------------
// proj V (round-0, unchanged)
// ---------------------------------------------------------------------------
__global__ __launch_bounds__(256, 2) void proj_v_kernel(
    const unsigned short* __restrict__ Wc, const unsigned short* __restrict__ Xp,
    const float* __restrict__ bh, unsigned short* __restrict__ V)
{
    const int b  = blockIdx.z;
    const int c0 = blockIdx.x * 128;
    const int p0 = blockIdx.y * 128;
    const int t  = threadIdx.x;
    const int wave = t >> 6, lane = t & 63, quad = lane >> 4, l16 = lane & 15;
    const int pw = p0 + wave * 32;

    f32x4 acc[2][8];
    #pragma unroll
    for (int ms = 0; ms < 2; ++ms)
        #pragma unroll
        for (int ns = 0; ns < 8; ++ns) acc[ms][ns] = (f32x4){0.f, 0.f, 0.f, 0.f};

    const unsigned short* xb = Xp + (size_t)b * 16 * (NPIX * 32);
    for (int st = 0; st < 16; ++st) {
        const unsigned short* xs = xb + (size_t)st * (NPIX * 32) + quad * 8;
        bf16x8 a0 = *(const bf16x8*)(xs + (size_t)(pw + l16) * 32);
        bf16x8 a1 = *(const bf16x8*)(xs + (size_t)(pw + 16 + l16) * 32);
        #pragma unroll
        for (int ns = 0; ns < 8; ++ns) {
            bf16x8 bb = *(const bf16x8*)&Wc[(size_t)(2 * HCH + c0 + ns * 16 + l16) * CH + st * 32 + quad * 8];
            acc[0][ns] = MFMA16(a0, bb, acc[0][ns]);
            acc[1][ns] = MFMA16(a1, bb, acc[1][ns]);
        }
    }

    float biasv[8];
    #pragma unroll
    for (int ns = 0; ns < 8; ++ns) biasv[ns] = bh[c0 + ns * 16 + l16];

    const int kb = pw >> 5;
    const int ko0 = quad * 4;
    #pragma unroll
    for (int ms = 0; ms < 2; ++ms) {
        #pragma unroll
        for (int ns = 0; ns < 8; ++ns) {
            const int c = c0 + ns * 16 + l16;
            ushort4 u = pack4(acc[ms][ns][0] + biasv[ns], acc[ms][ns][1] + biasv[ns],
                              acc[ms][ns][2] + biasv[ns], acc[ms][ns][3] + biasv[ns]);
            *(ushort4*)&V[((size_t)b * 128 + kb) * (CH * 32) + (size_t)c * 32 + ms * 16 + ko0] = u;
        }
    }
}

// ---------------------------------------------------------------------------
// Stats: EXACT round-0 version (64q, 512 thr, k-half split, grid 512).
// ---------------------------------------------------------------------------
__global__ __launch_bounds__(512, 4) void stats_kernel(
    const unsigned short* __restrict__ F, const unsigned short* __restrict__ G,
    float* __restrict__ rowl)
{
    const int blk = blockIdx.x;
    const int xcd = blk & 7;
    const int b   = xcd >> 1;
    const int kh  = xcd & 1;
    const int q0  = (blk >> 3) * 64;
    const int t    = threadIdx.x;
    const int wave = t >> 6, lane = t & 63, quad = lane >> 4, l16 = lane & 15;
    const int qh = wave >> 2, kw = wave & 3;

    bf16x8 af[2][8];
    #pragma unroll
    for (int qs = 0; qs < 2; ++qs)
        #pragma unroll
        for (int st = 0; st < 8; ++st)
            af[qs][st] = *(const bf16x8*)&F[((size_t)b * NPIX + q0 + qh * 32 + qs * 16 + l16) * HCH + st * 32 + quad * 8];

    float ls[2][4];
    #pragma unroll
    for (int qs = 0; qs < 2; ++qs)
        #pragma unroll
        for (int r = 0; r < 4; ++r) ls[qs][r] = 0.f;

    const unsigned short* Gb = G + (size_t)b * 8 * (NPIX * 32);
    const int kbeg = kh * 2048, kend = kbeg + 2048;
    for (int k0 = kbeg; k0 < kend; k0 += 128) {
        const int kk = k0 + kw * 32;
        f32x4 s[2][2];
        #pragma unroll
        for (int qs = 0; qs < 2; ++qs)
            #pragma unroll
            for (int ks = 0; ks < 2; ++ks) s[qs][ks] = (f32x4){0.f, 0.f, 0.f, 0.f};
        #pragma unroll
        for (int st = 0; st < 8; ++st) {
            const unsigned short* gs = Gb + (size_t)st * (NPIX * 32) + quad * 8;
            bf16x8 b0 = *(const bf16x8*)(gs + (size_t)(kk + l16) * 32);
            bf16x8 b1 = *(const bf16x8*)(gs + (size_t)(kk + 16 + l16) * 32);
            s[0][0] = MFMA16(af[0][st], b0, s[0][0]);
            s[1][0] = MFMA16(af[1][st], b0, s[1][0]);
            s[0][1] = MFMA16(af[0][st], b1, s[0][1]);
            s[1][1] = MFMA16(af[1][st], b1, s[1][1]);
        }
        #pragma unroll
        for (int qs = 0; qs < 2; ++qs)
            #pragma unroll
            for (int r = 0; r < 4; ++r)
                ls[qs][r] += exp2f(L2E * s[qs][0][r]) + exp2f(L2E * s[qs][1][r]);
    }

    #pragma unroll
    for (int d = 1; d < 16; d <<= 1)
        #pragma unroll
        for (int qs = 0; qs < 2; ++qs)
            #pragma unroll
            for (int r = 0; r < 4; ++r) ls[qs][r] += __shfl_xor(ls[qs][r], d, 64);

    if (l16 == 0) {
        #pragma unroll
        for (int qs = 0; qs < 2; ++qs)
            #pragma unroll
            for (int r = 0; r < 4; ++r)
                atomicAdd(&rowl[(size_t)b * NPIX + q0 + qh * 32 + qs * 16 + quad * 4 + r], ls[qs][r]);
    }
}

// ---------------------------------------------------------------------------
// Apply, q-split: 32q x 256c-half per block, 512 thr, grid 1024 -> 4 blk/CU
// (32 waves/CU). Per-wave state halves vs round-0 (O[2][2]=16 regs, s[2]=8),
// P LDS halves to [2][32][136]=17.4KB (4 blocks fit). F fragments loaded
// per-st from global (F tile 16KB is L1-resident; allocator remats instead
// of spilling -- round-1 lesson: NEVER add per-thread arrays here).
// Wave roles: all 8 waves share the 32-q tile; wave w owns k-strip 16
// (QK) and c-strip 32 (PV). One barrier per 128-key tile, double-buffered P.
// ---------------------------------------------------------------------------
__global__ __launch_bounds__(512, 4) void apply_kernel(
    const unsigned short* __restrict__ F, const unsigned short* __restrict__ G,
    const unsigned short* __restrict__ V, const float* __restrict__ rowl,
    float* __restrict__ outres, float* __restrict__ attnacc)
{
    __shared__ unsigned short P[2][32][136];   // 17,408 B
    const int blk = blockIdx.x;
    const int xcd = blk & 7;
    const int b   = xcd >> 1;
    const int ch  = xcd & 1;
    const int q0  = (blk >> 3) * 32;
    const int t    = threadIdx.x;
    const int wave = t >> 6, lane = t & 63, quad = lane >> 4, l16 = lane & 15;
    const int cw = ch * 256 + wave * 32;    // wave's 32-c strip (PV)

    float linv[2][4];
    #pragma unroll
    for (int qs = 0; qs < 2; ++qs)
        #pragma unroll
        for (int r = 0; r < 4; ++r)
            linv[qs][r] = 1.0f / rowl[(size_t)b * NPIX + q0 + qs * 16 + quad * 4 + r];

    f32x4 O[2][2];
    #pragma unroll
    for (int qs = 0; qs < 2; ++qs)
        #pragma unroll
        for (int ct = 0; ct < 2; ++ct) O[qs][ct] = (f32x4){0.f, 0.f, 0.f, 0.f};

    const unsigned short* Gb = G + (size_t)b * 8 * (NPIX * 32);
    const unsigned short* Vb = V + (size_t)b * 128 * (CH * 32);
    const unsigned short* Fq = F + ((size_t)b * NPIX + q0) * HCH;

    int buf = 0;
    for (int k0 = 0; k0 < NPIX; k0 += 128) {
        const int kk = k0 + wave * 16;      // wave's 16-k strip (QK)
        f32x4 s[2];
        s[0] = (f32x4){0.f, 0.f, 0.f, 0.f};
        s[1] = (f32x4){0.f, 0.f, 0.f, 0.f};
        #pragma unroll
        for (int st = 0; st < 8; ++st) {
            bf16x8 a0 = *(const bf16x8*)&Fq[(size_t)l16 * HCH + st * 32 + quad * 8];
            bf16x8 a1 = *(const bf16x8*)&Fq[(size_t)(16 + l16) * HCH + st * 32 + quad * 8];
            bf16x8 bg = *(const bf16x8*)(Gb + (size_t)st * (NPIX * 32) + (size_t)(kk + l16) * 32 + quad * 8);
            s[0] = MFMA16(a0, bg, s[0]);
            s[1] = MFMA16(a1, bg, s[1]);
        }

        float p[2][4];
        #pragma unroll
        for (int qs = 0; qs < 2; ++qs)
            #pragma unroll
            for (int r = 0; r < 4; ++r)
                p[qs][r] = exp2f(L2E * s[qs][r]) * linv[qs][r];

        #pragma unroll
        for (int qs = 0; qs < 2; ++qs)
            #pragma unroll
            for (int r = 0; r < 4; ++r)
                P[buf][qs * 16 + quad * 4 + r][wave * 16 + l16] = f2bf(p[qs][r]);

        if (ch == 0) {
            float cs = p[0][0] + p[0][1] + p[0][2] + p[0][3]
                     + p[1][0] + p[1][1] + p[1][2] + p[1][3];
            cs += __shfl_xor(cs, 16, 64);
            cs += __shfl_xor(cs, 32, 64);
            if (quad == 0)
                atomicAdd(&attnacc[(size_t)b * NPIX + kk + l16], cs);
        }

        __syncthreads();   // P[buf] complete; next iter writes buf^1 (race-free)

        #pragma unroll
        for (int ks = 0; ks < 4; ++ks) {
            bf16x8 pa0 = *(const bf16x8*)&P[buf][l16][ks * 32 + quad * 8];
            bf16x8 pa1 = *(const bf16x8*)&P[buf][16 + l16][ks * 32 + quad * 8];
            const unsigned short* vs = Vb + ((size_t)(k0 >> 5) + ks) * (CH * 32) + quad * 8;
            #pragma unroll
            for (int ct = 0; ct < 2; ++ct) {
                bf16x8 vb = *(const bf16x8*)(vs + (size_t)(cw + ct * 16 + l16) * 32);
                O[0][ct] = MFMA16(pa0, vb, O[0][ct]);
                O[1][ct] = MFMA16(pa1, vb, O[1][ct]);
            }
        }
        buf ^= 1;
    }

    #pragma unroll
    for (int qs = 0; qs < 2; ++qs) {
        #pragma unroll
        for (int ct = 0; ct < 2; ++ct) {
            const int c = cw + ct * 16 + l16;
            *(f32x4*)&outres[((size_t)b * CH + c) * NPIX + q0 + qs * 16 + quad * 4] = O[qs][ct];
        }
    }
}

__global__ __launch_bounds__(256) void attn_fin_kernel(
    const float* __restrict__ acc, float* __restrict__ outa)
{
    const int i = blockIdx.x * 256 + threadIdx.x;
    if (i < BATCH * NPIX) outa[i] = acc[i] * (1.0f / (float)NPIX);
}

extern "C" void kernel_launch(void* const* d_in, const int* in_sizes, int n_in,
                              void* d_out, int out_size, void* d_ws, size_t ws_size,
                              hipStream_t stream)
{
    (void)in_sizes; (void)n_in; (void)out_size; (void)ws_size;
    const float* x  = (const float*)d_in[0];
    const float* Wf = (const float*)d_in[1];
    const float* bf = (const float*)d_in[2];
    const float* Wg = (const float*)d_in[3];
    const float* bg = (const float*)d_in[4];
    const float* Wh = (const float*)d_in[5];
    const float* bh = (const float*)d_in[6];
    float* out = (float*)d_out;

    unsigned short* Xp = (unsigned short*)d_ws;                      // 4*16*4096*32
    unsigned short* Wc = Xp + (size_t)BATCH * 16 * NPIX * 32;        // 1024*512
    unsigned short* F  = Wc + (size_t)1024 * CH;                     // 4*4096*256
    unsigned short* G  = F + (size_t)BATCH * NPIX * HCH;             // 4*8*4096*32
    unsigned short* V  = G + (size_t)BATCH * NPIX * HCH;             // 4*128*512*32
    float* rowl    = (float*)(V + (size_t)BATCH * NPIX * CH);        // 4*4096
    float* attnacc = rowl + (size_t)BATCH * NPIX;                    // 4*4096

    hipMemsetAsync(rowl, 0, (size_t)2 * BATCH * NPIX * sizeof(float), stream);

    convert_w_kernel<<<512, 256, 0, stream>>>(Wf, Wg, Wh, Wc);
    convert_x_kernel<<<dim3(NPIX / 64, 16, BATCH), 256, 0, stream>>>(x, Xp);

    proj_fg_kernel<<<dim3(NPIX / 128, 4, BATCH), 256, 0, stream>>>(Wc, Xp, bf, bg, F, G);
    proj_v_kernel<<<dim3(4, NPIX / 128, BATCH), 256, 0, stream>>>(Wc, Xp, bh, V);

    stats_kernel<<<512, 512, 0, stream>>>(F, G, rowl);
    apply_kernel<<<1024, 512, 0, stream>>>(F, G, V, rowl, out, attnacc);

    attn_fin_kernel<<<BATCH * NPIX / 256, 256, 0, stream>>>(
        attnacc, out + (size_t)BATCH * CH * NPIX);
}

// Round 3
// 550.913 us; speedup vs baseline: 1.3339x; 1.0069x over previous
//
#include <hip/hip_runtime.h>
#include <cmath>

#define BATCH 4
#define CH    512
#define HCH   256
#define NPIX  4096
#define L2E   1.44269504088896340736f

typedef __attribute__((ext_vector_type(8))) short bf16x8;
typedef __attribute__((ext_vector_type(4))) float f32x4;

#define MFMA16(a, b, c) __builtin_amdgcn_mfma_f32_16x16x32_bf16((a), (b), (c), 0, 0, 0)

__device__ __forceinline__ unsigned short f2bf(float f) {
    unsigned int u = __float_as_uint(f);
    return (unsigned short)((u + 0x7fffu + ((u >> 16) & 1u)) >> 16);
}
__device__ __forceinline__ ushort4 pack4(float a, float b, float c, float d) {
    ushort4 u; u.x = f2bf(a); u.y = f2bf(b); u.z = f2bf(c); u.w = f2bf(d); return u;
}

// ---------------------------------------------------------------------------
// Wc[1024][512] bf16 = concat(Wf, Wg, Wh) rows, K-contiguous.
// ---------------------------------------------------------------------------
__global__ __launch_bounds__(256) void convert_w_kernel(
    const float* __restrict__ Wf, const float* __restrict__ Wg,
    const float* __restrict__ Wh, unsigned short* __restrict__ Wc)
{
    const int idx = blockIdx.x * 256 + threadIdx.x;
    const int o  = idx >> 7;
    const int c4 = (idx & 127) * 4;
    const float* src = (o < HCH)     ? (Wf + (size_t)o * CH + c4)
                     : (o < 2 * HCH) ? (Wg + (size_t)(o - HCH) * CH + c4)
                                     : (Wh + (size_t)(o - 2 * HCH) * CH + c4);
    float4 v = *(const float4*)src;
    *(ushort4*)&Wc[(size_t)o * CH + c4] = pack4(v.x, v.y, v.z, v.w);
}

// ---------------------------------------------------------------------------
// X' swizzle: x fp32 [b][512][4096] -> bf16 [b][cb=16][n=4096][co=32].
// ---------------------------------------------------------------------------
__global__ __launch_bounds__(256) void convert_x_kernel(
    const float* __restrict__ x, unsigned short* __restrict__ Xp)
{
    __shared__ unsigned short Lt[64][40];
    const int b  = blockIdx.z;
    const int cb = blockIdx.y;
    const int n0 = blockIdx.x * 64;
    const int t  = threadIdx.x;
    const int cr = t >> 4;
    const int f4 = t & 15;
    #pragma unroll
    for (int p = 0; p < 2; ++p) {
        const int c = p * 16 + cr;
        float4 v = *(const float4*)(x + ((size_t)b * CH + cb * 32 + c) * NPIX + n0 + f4 * 4);
        Lt[f4 * 4 + 0][c] = f2bf(v.x);
        Lt[f4 * 4 + 1][c] = f2bf(v.y);
        Lt[f4 * 4 + 2][c] = f2bf(v.z);
        Lt[f4 * 4 + 3][c] = f2bf(v.w);
    }
    __syncthreads();
    const int n  = t >> 2;
    const int ch = t & 3;
    uint4 u = *(const uint4*)&Lt[n][ch * 8];
    *(uint4*)&Xp[((size_t)b * 16 + cb) * (NPIX * 32) + (size_t)(n0 + n) * 32 + ch * 8] = u;
}

// ---------------------------------------------------------------------------
// proj F/G (unchanged)
// ---------------------------------------------------------------------------
__global__ __launch_bounds__(256, 2) void proj_fg_kernel(
    const unsigned short* __restrict__ Wc, const unsigned short* __restrict__ Xp,
    const float* __restrict__ bf, const float* __restrict__ bg,
    unsigned short* __restrict__ F, unsigned short* __restrict__ G)
{
    const int b  = blockIdx.z;
    const int n0 = blockIdx.x * 128;
    const int o0 = blockIdx.y * 128;
    const int t  = threadIdx.x;
    const int wave = t >> 6, lane = t & 63, quad = lane >> 4, l16 = lane & 15;
    const int ow = o0 + wave * 32;

    f32x4 acc[2][8];
    #pragma unroll
    for (int ms = 0; ms < 2; ++ms)
        #pragma unroll
        for (int ns = 0; ns < 8; ++ns) acc[ms][ns] = (f32x4){0.f, 0.f, 0.f, 0.f};

    const unsigned short* xb = Xp + (size_t)b * 16 * (NPIX * 32);
    for (int st = 0; st < 16; ++st) {
        bf16x8 a0 = *(const bf16x8*)&Wc[(size_t)(ow + l16) * CH + st * 32 + quad * 8];
        bf16x8 a1 = *(const bf16x8*)&Wc[(size_t)(ow + 16 + l16) * CH + st * 32 + quad * 8];
        const unsigned short* xs = xb + (size_t)st * (NPIX * 32) + quad * 8;
        #pragma unroll
        for (int ns = 0; ns < 8; ++ns) {
            bf16x8 bb = *(const bf16x8*)(xs + (size_t)(n0 + ns * 16 + l16) * 32);
            acc[0][ns] = MFMA16(a0, bb, acc[0][ns]);
            acc[1][ns] = MFMA16(a1, bb, acc[1][ns]);
        }
    }

    const int orow = quad * 4;
    #pragma unroll
    for (int ms = 0; ms < 2; ++ms) {
        const int ob = ow + ms * 16 + orow;
        float bias[4];
        #pragma unroll
        for (int r = 0; r < 4; ++r)
            bias[r] = (o0 < HCH) ? bf[ob + r] : bg[ob + r - HCH];
        #pragma unroll
        for (int ns = 0; ns < 8; ++ns) {
            const int n = n0 + ns * 16 + l16;
            ushort4 u = pack4(acc[ms][ns][0] + bias[0], acc[ms][ns][1] + bias[1],
                              acc[ms][ns][2] + bias[2], acc[ms][ns][3] + bias[3]);
            if (o0 < HCH) {
                *(ushort4*)&F[((size_t)b * NPIX + n) * HCH + ob] = u;
            } else {
                const int og = ob - HCH;
                const int cb = og >> 5, co = og & 31;
                *(ushort4*)&G[((size_t)b * 8 + cb) * (NPIX * 32) + (size_t)n * 32 + co] = u;
            }
        }
    }
}

// ---------------------------------------------------------------------------
// proj V (unchanged)
// ---------------------------------------------------------------------------
__global__ __launch_bounds__(256, 2) void proj_v_kernel(
    const unsigned short* __restrict__ Wc, const unsigned short* __restrict__ Xp,
    const float* __restrict__ bh, unsigned short* __restrict__ V)
{
    const int b  = blockIdx.z;
    const int c0 = blockIdx.x * 128;
    const int p0 = blockIdx.y * 128;
    const int t  = threadIdx.x;
    const int wave = t >> 6, lane = t & 63, quad = lane >> 4, l16 = lane & 15;
    const int pw = p0 + wave * 32;

    f32x4 acc[2][8];
    #pragma unroll
    for (int ms = 0; ms < 2; ++ms)
        #pragma unroll
        for (int ns = 0; ns < 8; ++ns) acc[ms][ns] = (f32x4){0.f, 0.f, 0.f, 0.f};

    const unsigned short* xb = Xp + (size_t)b * 16 * (NPIX * 32);
    for (int st = 0; st < 16; ++st) {
        const unsigned short* xs = xb + (size_t)st * (NPIX * 32) + quad * 8;
        bf16x8 a0 = *(const bf16x8*)(xs + (size_t)(pw + l16) * 32);
        bf16x8 a1 = *(const bf16x8*)(xs + (size_t)(pw + 16 + l16) * 32);
        #pragma unroll
        for (int ns = 0; ns < 8; ++ns) {
            bf16x8 bb = *(const bf16x8*)&Wc[(size_t)(2 * HCH + c0 + ns * 16 + l16) * CH + st * 32 + quad * 8];
            acc[0][ns] = MFMA16(a0, bb, acc[0][ns]);
            acc[1][ns] = MFMA16(a1, bb, acc[1][ns]);
        }
    }

    float biasv[8];
    #pragma unroll
    for (int ns = 0; ns < 8; ++ns) biasv[ns] = bh[c0 + ns * 16 + l16];

    const int kb = pw >> 5;
    const int ko0 = quad * 4;
    #pragma unroll
    for (int ms = 0; ms < 2; ++ms) {
        #pragma unroll
        for (int ns = 0; ns < 8; ++ns) {
            const int c = c0 + ns * 16 + l16;
            ushort4 u = pack4(acc[ms][ns][0] + biasv[ns], acc[ms][ns][1] + biasv[ns],
                              acc[ms][ns][2] + biasv[ns], acc[ms][ns][3] + biasv[ns]);
            *(ushort4*)&V[((size_t)b * 128 + kb) * (CH * 32) + (size_t)c * 32 + ms * 16 + ko0] = u;
        }
    }
}

// ---------------------------------------------------------------------------
// score: QK^T computed ONCE. S -> exp2 -> bf16 P written to HBM (layout
// [b][kb=128][q=4096][ko=32], full-64B-line writes via offset-immediate
// store_short), rowl += rowsums. stats-kernel structure (64q, k-half split,
// grid 512, no LDS, no barriers). linv deferred to pv epilogue.
// ---------------------------------------------------------------------------
__global__ __launch_bounds__(512, 4) void score_kernel(
    const unsigned short* __restrict__ F, const unsigned short* __restrict__ G,
    unsigned short* __restrict__ P, float* __restrict__ rowl)
{
    const int blk = blockIdx.x;
    const int xcd = blk & 7;
    const int b   = xcd >> 1;
    const int kh  = xcd & 1;
    const int q0  = (blk >> 3) * 64;
    const int t    = threadIdx.x;
    const int wave = t >> 6, lane = t & 63, quad = lane >> 4, l16 = lane & 15;
    const int qh = wave >> 2, kw = wave & 3;

    bf16x8 af[2][8];
    #pragma unroll
    for (int qs = 0; qs < 2; ++qs)
        #pragma unroll
        for (int st = 0; st < 8; ++st)
            af[qs][st] = *(const bf16x8*)&F[((size_t)b * NPIX + q0 + qh * 32 + qs * 16 + l16) * HCH + st * 32 + quad * 8];

    float ls[2][4];
    #pragma unroll
    for (int qs = 0; qs < 2; ++qs)
        #pragma unroll
        for (int r = 0; r < 4; ++r) ls[qs][r] = 0.f;

    const unsigned short* Gb = G + (size_t)b * 8 * (NPIX * 32);
    unsigned short* Pbase = P + (size_t)b * 128 * (NPIX * 32)
                              + ((size_t)(q0 + qh * 32 + quad * 4)) * 32 + l16;

    const int kbeg = kh * 2048, kend = kbeg + 2048;
    for (int k0 = kbeg; k0 < kend; k0 += 128) {
        const int kk = k0 + kw * 32;
        f32x4 s[2][2];
        #pragma unroll
        for (int qs = 0; qs < 2; ++qs)
            #pragma unroll
            for (int ks = 0; ks < 2; ++ks) s[qs][ks] = (f32x4){0.f, 0.f, 0.f, 0.f};
        #pragma unroll
        for (int st = 0; st < 8; ++st) {
            const unsigned short* gs = Gb + (size_t)st * (NPIX * 32) + quad * 8;
            bf16x8 b0 = *(const bf16x8*)(gs + (size_t)(kk + l16) * 32);
            bf16x8 b1 = *(const bf16x8*)(gs + (size_t)(kk + 16 + l16) * 32);
            s[0][0] = MFMA16(af[0][st], b0, s[0][0]);
            s[1][0] = MFMA16(af[1][st], b0, s[1][0]);
            s[0][1] = MFMA16(af[0][st], b1, s[0][1]);
            s[1][1] = MFMA16(af[1][st], b1, s[1][1]);
        }

        // P tile store: kb = kk>>5; elem = kb*NPIX*32 + (q)*32 + ks*16 + l16.
        // All (qs,ks,r) offsets are compile-time immediates from one base.
        unsigned short* pw = Pbase + (size_t)(kk >> 5) * (NPIX * 32);
        #pragma unroll
        for (int qs = 0; qs < 2; ++qs)
            #pragma unroll
            for (int ks = 0; ks < 2; ++ks)
                #pragma unroll
                for (int r = 0; r < 4; ++r) {
                    float e = exp2f(L2E * s[qs][ks][r]);
                    pw[qs * 512 + r * 32 + ks * 16] = f2bf(e);
                    ls[qs][r] += e;
                }
    }

    #pragma unroll
    for (int d = 1; d < 16; d <<= 1)
        #pragma unroll
        for (int qs = 0; qs < 2; ++qs)
            #pragma unroll
            for (int r = 0; r < 4; ++r) ls[qs][r] += __shfl_xor(ls[qs][r], d, 64);

    if (l16 == 0) {
        #pragma unroll
        for (int qs = 0; qs < 2; ++qs)
            #pragma unroll
            for (int r = 0; r < 4; ++r)
                atomicAdd(&rowl[(size_t)b * NPIX + q0 + qh * 32 + qs * 16 + quad * 4 + r], ls[qs][r]);
    }
}

// ---------------------------------------------------------------------------
// pv: pure streaming GEMM O[q][c] = P(4096x4096) x V(4096x512), linv[q]
// applied to O in epilogue (algebraically = normalizing P rows). No LDS,
// no barriers, 8 independent MFMA chains; 8 MFMA : 6 loads per 32-k step.
// Block: 64q x 256c (8 waves = 2qw x 4cw, wave tile 32q x 64c, O=32 AGPR).
// Grid 512 -> 2 blk/CU; xcd = (b,ch): per-XCD V panel 2MB L2-resident,
// P streams from HBM (read 2x total = 268MB).
// ---------------------------------------------------------------------------
__global__ __launch_bounds__(512, 4) void pv_kernel(
    const unsigned short* __restrict__ P, const unsigned short* __restrict__ V,
    const float* __restrict__ rowl, float* __restrict__ outres)
{
    const int blk = blockIdx.x;
    const int xcd = blk & 7;
    const int b   = xcd >> 1;
    const int ch  = xcd & 1;
    const int q0  = (blk >> 3) * 64;
    const int t    = threadIdx.x;
    const int wave = t >> 6, lane = t & 63, quad = lane >> 4, l16 = lane & 15;
    const int qw = wave >> 2;              // 0..1 -> 32q
    const int cw = wave & 3;               // 0..3 -> 64c
    const int cbase = ch * 256 + cw * 64;

    f32x4 O[2][4];
    #pragma unroll
    for (int qs = 0; qs < 2; ++qs)
        #pragma unroll
        for (int ct = 0; ct < 4; ++ct) O[qs][ct] = (f32x4){0.f, 0.f, 0.f, 0.f};

    const unsigned short* pa = P + ((size_t)b * 128 * NPIX + (q0 + qw * 32 + l16)) * 32 + quad * 8;
    const unsigned short* vb = V + ((size_t)b * 128 * CH + (cbase + l16)) * 32 + quad * 8;

    #pragma unroll 2
    for (int kb = 0; kb < 128; ++kb) {
        bf16x8 a0 = *(const bf16x8*)(pa);
        bf16x8 a1 = *(const bf16x8*)(pa + 512);
        bf16x8 v0 = *(const bf16x8*)(vb);
        bf16x8 v1 = *(const bf16x8*)(vb + 512);
        bf16x8 v2 = *(const bf16x8*)(vb + 1024);
        bf16x8 v3 = *(const bf16x8*)(vb + 1536);
        O[0][0] = MFMA16(a0, v0, O[0][0]);
        O[1][0] = MFMA16(a1, v0, O[1][0]);
        O[0][1] = MFMA16(a0, v1, O[0][1]);
        O[1][1] = MFMA16(a1, v1, O[1][1]);
        O[0][2] = MFMA16(a0, v2, O[0][2]);
        O[1][2] = MFMA16(a1, v2, O[1][2]);
        O[0][3] = MFMA16(a0, v3, O[0][3]);
        O[1][3] = MFMA16(a1, v3, O[1][3]);
        pa += (size_t)NPIX * 32;
        vb += (size_t)CH * 32;
    }

    float lr[2][4];
    #pragma unroll
    for (int qs = 0; qs < 2; ++qs)
        #pragma unroll
        for (int r = 0; r < 4; ++r)
            lr[qs][r] = 1.0f / rowl[(size_t)b * NPIX + q0 + qw * 32 + qs * 16 + quad * 4 + r];

    #pragma unroll
    for (int qs = 0; qs < 2; ++qs) {
        #pragma unroll
        for (int ct = 0; ct < 4; ++ct) {
            f32x4 o = O[qs][ct];
            o[0] *= lr[qs][0]; o[1] *= lr[qs][1]; o[2] *= lr[qs][2]; o[3] *= lr[qs][3];
            const int c = cbase + ct * 16 + l16;
            *(f32x4*)&outres[((size_t)b * CH + c) * NPIX + q0 + qw * 32 + qs * 16 + quad * 4] = o;
        }
    }
}

// ---------------------------------------------------------------------------
// colsum: attnacc[b][k] = sum_q P[b][q][k] * linv[q]. One block per (b,kb):
// reads the 4096x32 panel coalesced (uint = 2 bf16 per thread), LDS reduce,
// single write (no atomics). ~134MB read, memory-bound.
// ---------------------------------------------------------------------------
__global__ __launch_bounds__(256) void colsum_kernel(
    const unsigned short* __restrict__ P, const float* __restrict__ rowl,
    float* __restrict__ attnacc)
{
    __shared__ float CS[16][32];
    const int blk = blockIdx.x;            // b*128 + kb
    const int b  = blk >> 7;
    const int kb = blk & 127;
    const int t  = threadIdx.x;
    const int ko2 = t & 15;                // ko pair: 2*ko2, 2*ko2+1
    const int qr  = t >> 4;                // 0..15
    const unsigned short* Pb = P + (size_t)(b * 128 + kb) * (NPIX * 32);
    const float* rl = rowl + (size_t)b * NPIX;

    float a0 = 0.f, a1 = 0.f;
    for (int q = qr; q < NPIX; q += 16) {
        unsigned int u = *(const unsigned int*)(Pb + (size_t)q * 32 + ko2 * 2);
        float li = 1.0f / rl[q];
        a0 += __uint_as_float(u << 16) * li;
        a1 += __uint_as_float(u & 0xFFFF0000u) * li;
    }
    CS[qr][ko2 * 2]     = a0;
    CS[qr][ko2 * 2 + 1] = a1;
    __syncthreads();
    if (t < 32) {
        float s = 0.f;
        #pragma unroll
        for (int i = 0; i < 16; ++i) s += CS[i][t];
        attnacc[(size_t)b * NPIX + kb * 32 + t] = s;
    }
}

// ---------------------------------------------------------------------------
// FALLBACK path (used only if ws_size too small for P): round-2 stats+apply.
// ---------------------------------------------------------------------------
__global__ __launch_bounds__(512, 4) void stats_kernel(
    const unsigned short* __restrict__ F, const unsigned short* __restrict__ G,
    float* __restrict__ rowl)
{
    const int blk = blockIdx.x;
    const int xcd = blk & 7;
    const int b   = xcd >> 1;
    const int kh  = xcd & 1;
    const int q0  = (blk >> 3) * 64;
    const int t    = threadIdx.x;
    const int wave = t >> 6, lane = t & 63, quad = lane >> 4, l16 = lane & 15;
    const int qh = wave >> 2, kw = wave & 3;

    bf16x8 af[2][8];
    #pragma unroll
    for (int qs = 0; qs < 2; ++qs)
        #pragma unroll
        for (int st = 0; st < 8; ++st)
            af[qs][st] = *(const bf16x8*)&F[((size_t)b * NPIX + q0 + qh * 32 + qs * 16 + l16) * HCH + st * 32 + quad * 8];

    float ls[2][4];
    #pragma unroll
    for (int qs = 0; qs < 2; ++qs)
        #pragma unroll
        for (int r = 0; r < 4; ++r) ls[qs][r] = 0.f;

    const unsigned short* Gb = G + (size_t)b * 8 * (NPIX * 32);
    const int kbeg = kh * 2048, kend = kbeg + 2048;
    for (int k0 = kbeg; k0 < kend; k0 += 128) {
        const int kk = k0 + kw * 32;
        f32x4 s[2][2];
        #pragma unroll
        for (int qs = 0; qs < 2; ++qs)
            #pragma unroll
            for (int ks = 0; ks < 2; ++ks) s[qs][ks] = (f32x4){0.f, 0.f, 0.f, 0.f};
        #pragma unroll
        for (int st = 0; st < 8; ++st) {
            const unsigned short* gs = Gb + (size_t)st * (NPIX * 32) + quad * 8;
            bf16x8 b0 = *(const bf16x8*)(gs + (size_t)(kk + l16) * 32);
            bf16x8 b1 = *(const bf16x8*)(gs + (size_t)(kk + 16 + l16) * 32);
            s[0][0] = MFMA16(af[0][st], b0, s[0][0]);
            s[1][0] = MFMA16(af[1][st], b0, s[1][0]);
            s[0][1] = MFMA16(af[0][st], b1, s[0][1]);
            s[1][1] = MFMA16(af[1][st], b1, s[1][1]);
        }
        #pragma unroll
        for (int qs = 0; qs < 2; ++qs)
            #pragma unroll
            for (int r = 0; r < 4; ++r)
                ls[qs][r] += exp2f(L2E * s[qs][0][r]) + exp2f(L2E * s[qs][1][r]);
    }

    #pragma unroll
    for (int d = 1; d < 16; d <<= 1)
        #pragma unroll
        for (int qs = 0; qs < 2; ++qs)
            #pragma unroll
            for (int r = 0; r < 4; ++r) ls[qs][r] += __shfl_xor(ls[qs][r], d, 64);

    if (l16 == 0) {
        #pragma unroll
        for (int qs = 0; qs < 2; ++qs)
            #pragma unroll
            for (int r = 0; r < 4; ++r)
                atomicAdd(&rowl[(size_t)b * NPIX + q0 + qh * 32 + qs * 16 + quad * 4 + r], ls[qs][r]);
    }
}

__global__ __launch_bounds__(512, 4) void apply_kernel(
    const unsigned short* __restrict__ F, const unsigned short* __restrict__ G,
    const unsigned short* __restrict__ V, const float* __restrict__ rowl,
    float* __restrict__ outres, float* __restrict__ attnacc)
{
    __shared__ unsigned short Pl[2][32][136];
    const int blk = blockIdx.x;
    const int xcd = blk & 7;
    const int b   = xcd >> 1;
    const int ch  = xcd & 1;
    const int q0  = (blk >> 3) * 32;
    const int t    = threadIdx.x;
    const int wave = t >> 6, lane = t & 63, quad = lane >> 4, l16 = lane & 15;
    const int cw = ch * 256 + wave * 32;

    float linv[2][4];
    #pragma unroll
    for (int qs = 0; qs < 2; ++qs)
        #pragma unroll
        for (int r = 0; r < 4; ++r)
            linv[qs][r] = 1.0f / rowl[(size_t)b * NPIX + q0 + qs * 16 + quad * 4 + r];

    f32x4 O[2][2];
    #pragma unroll
    for (int qs = 0; qs < 2; ++qs)
        #pragma unroll
        for (int ct = 0; ct < 2; ++ct) O[qs][ct] = (f32x4){0.f, 0.f, 0.f, 0.f};

    const unsigned short* Gb = G + (size_t)b * 8 * (NPIX * 32);
    const unsigned short* Vb = V + (size_t)b * 128 * (CH * 32);
    const unsigned short* Fq = F + ((size_t)b * NPIX + q0) * HCH;

    int buf = 0;
    for (int k0 = 0; k0 < NPIX; k0 += 128) {
        const int kk = k0 + wave * 16;
        f32x4 s[2];
        s[0] = (f32x4){0.f, 0.f, 0.f, 0.f};
        s[1] = (f32x4){0.f, 0.f, 0.f, 0.f};
        #pragma unroll
        for (int st = 0; st < 8; ++st) {
            bf16x8 a0 = *(const bf16x8*)&Fq[(size_t)l16 * HCH + st * 32 + quad * 8];
            bf16x8 a1 = *(const bf16x8*)&Fq[(size_t)(16 + l16) * HCH + st * 32 + quad * 8];
            bf16x8 bg = *(const bf16x8*)(Gb + (size_t)st * (NPIX * 32) + (size_t)(kk + l16) * 32 + quad * 8);
            s[0] = MFMA16(a0, bg, s[0]);
            s[1] = MFMA16(a1, bg, s[1]);
        }

        float p[2][4];
        #pragma unroll
        for (int qs = 0; qs < 2; ++qs)
            #pragma unroll
            for (int r = 0; r < 4; ++r)
                p[qs][r] = exp2f(L2E * s[qs][r]) * linv[qs][r];

        #pragma unroll
        for (int qs = 0; qs < 2; ++qs)
            #pragma unroll
            for (int r = 0; r < 4; ++r)
                Pl[buf][qs * 16 + quad * 4 + r][wave * 16 + l16] = f2bf(p[qs][r]);

        if (ch == 0) {
            float cs = p[0][0] + p[0][1] + p[0][2] + p[0][3]
                     + p[1][0] + p[1][1] + p[1][2] + p[1][3];
            cs += __shfl_xor(cs, 16, 64);
            cs += __shfl_xor(cs, 32, 64);
            if (quad == 0)
                atomicAdd(&attnacc[(size_t)b * NPIX + kk + l16], cs);
        }

        __syncthreads();

        #pragma unroll
        for (int ks = 0; ks < 4; ++ks) {
            bf16x8 pa0 = *(const bf16x8*)&Pl[buf][l16][ks * 32 + quad * 8];
            bf16x8 pa1 = *(const bf16x8*)&Pl[buf][16 + l16][ks * 32 + quad * 8];
            const unsigned short* vs = Vb + ((size_t)(k0 >> 5) + ks) * (CH * 32) + quad * 8;
            #pragma unroll
            for (int ct = 0; ct < 2; ++ct) {
                bf16x8 vv = *(const bf16x8*)(vs + (size_t)(cw + ct * 16 + l16) * 32);
                O[0][ct] = MFMA16(pa0, vv, O[0][ct]);
                O[1][ct] = MFMA16(pa1, vv, O[1][ct]);
            }
        }
        buf ^= 1;
    }

    #pragma unroll
    for (int qs = 0; qs < 2; ++qs) {
        #pragma unroll
        for (int ct = 0; ct < 2; ++ct) {
            const int c = cw + ct * 16 + l16;
            *(f32x4*)&outres[((size_t)b * CH + c) * NPIX + q0 + qs * 16 + quad * 4] = O[qs][ct];
        }
    }
}

__global__ __launch_bounds__(256) void attn_fin_kernel(
    const float* __restrict__ acc, float* __restrict__ outa)
{
    const int i = blockIdx.x * 256 + threadIdx.x;
    if (i < BATCH * NPIX) outa[i] = acc[i] * (1.0f / (float)NPIX);
}

extern "C" void kernel_launch(void* const* d_in, const int* in_sizes, int n_in,
                              void* d_out, int out_size, void* d_ws, size_t ws_size,
                              hipStream_t stream)
{
    (void)in_sizes; (void)n_in; (void)out_size;
    const float* x  = (const float*)d_in[0];
    const float* Wf = (const float*)d_in[1];
    const float* bf = (const float*)d_in[2];
    const float* Wg = (const float*)d_in[3];
    const float* bg = (const float*)d_in[4];
    const float* Wh = (const float*)d_in[5];
    const float* bh = (const float*)d_in[6];
    float* out = (float*)d_out;

    const size_t P_ELEMS  = (size_t)BATCH * 128 * NPIX * 32;   // 67,108,864
    const size_t XP_ELEMS = (size_t)BATCH * 16 * NPIX * 32;    //  8,388,608
    const size_t F_ELEMS  = (size_t)BATCH * NPIX * HCH;        //  4,194,304
    const size_t V_ELEMS  = (size_t)BATCH * 128 * CH * 32;     //  8,388,608
    const size_t NEED = (P_ELEMS + 2 * F_ELEMS + V_ELEMS) * 2
                      + (size_t)2 * BATCH * NPIX * 4;          // ~167.9 MB

    if (ws_size >= NEED) {
        // ---- materialized-P path. P overlays Xp+Wc (dead before score).
        unsigned short* P  = (unsigned short*)d_ws;
        unsigned short* Xp = P;
        unsigned short* Wc = P + XP_ELEMS;
        unsigned short* F  = P + P_ELEMS;
        unsigned short* G  = F + F_ELEMS;
        unsigned short* V  = G + F_ELEMS;
        float* rowl    = (float*)(V + V_ELEMS);
        float* attnacc = rowl + (size_t)BATCH * NPIX;

        hipMemsetAsync(rowl, 0, (size_t)BATCH * NPIX * sizeof(float), stream);

        convert_w_kernel<<<512, 256, 0, stream>>>(Wf, Wg, Wh, Wc);
        convert_x_kernel<<<dim3(NPIX / 64, 16, BATCH), 256, 0, stream>>>(x, Xp);

        proj_fg_kernel<<<dim3(NPIX / 128, 4, BATCH), 256, 0, stream>>>(Wc, Xp, bf, bg, F, G);
        proj_v_kernel<<<dim3(4, NPIX / 128, BATCH), 256, 0, stream>>>(Wc, Xp, bh, V);

        score_kernel<<<512, 512, 0, stream>>>(F, G, P, rowl);
        pv_kernel<<<512, 512, 0, stream>>>(P, V, rowl, out);
        colsum_kernel<<<512, 256, 0, stream>>>(P, rowl, attnacc);

        attn_fin_kernel<<<BATCH * NPIX / 256, 256, 0, stream>>>(
            attnacc, out + (size_t)BATCH * CH * NPIX);
    } else {
        // ---- fallback: round-2 layout & kernels.
        unsigned short* Xp = (unsigned short*)d_ws;
        unsigned short* Wc = Xp + XP_ELEMS;
        unsigned short* F  = Wc + (size_t)1024 * CH;
        unsigned short* G  = F + F_ELEMS;
        unsigned short* V  = G + F_ELEMS;
        float* rowl    = (float*)(V + V_ELEMS);
        float* attnacc = rowl + (size_t)BATCH * NPIX;

        hipMemsetAsync(rowl, 0, (size_t)2 * BATCH * NPIX * sizeof(float), stream);

        convert_w_kernel<<<512, 256, 0, stream>>>(Wf, Wg, Wh, Wc);
        convert_x_kernel<<<dim3(NPIX / 64, 16, BATCH), 256, 0, stream>>>(x, Xp);

        proj_fg_kernel<<<dim3(NPIX / 128, 4, BATCH), 256, 0, stream>>>(Wc, Xp, bf, bg, F, G);
        proj_v_kernel<<<dim3(4, NPIX / 128, BATCH), 256, 0, stream>>>(Wc, Xp, bh, V);

        stats_kernel<<<512, 512, 0, stream>>>(F, G, rowl);
        apply_kernel<<<1024, 512, 0, stream>>>(F, G, V, rowl, out, attnacc);

        attn_fin_kernel<<<BATCH * NPIX / 256, 256, 0, stream>>>(
            attnacc, out + (size_t)BATCH * CH * NPIX);
    }
}

// Round 4
// 529.655 us; speedup vs baseline: 1.3874x; 1.0401x over previous
//
#include <hip/hip_runtime.h>
#include <cmath>

#define BATCH 4
#define CH    512
#define HCH   256
#define NPIX  4096
#define L2E   1.44269504088896340736f

typedef __attribute__((ext_vector_type(8))) short bf16x8;
typedef __attribute__((ext_vector_type(4))) float f32x4;

#define MFMA16(a, b, c) __builtin_amdgcn_mfma_f32_16x16x32_bf16((a), (b), (c), 0, 0, 0)

__device__ __forceinline__ unsigned short f2bf(float f) {
    unsigned int u = __float_as_uint(f);
    return (unsigned short)((u + 0x7fffu + ((u >> 16) & 1u)) >> 16);
}
__device__ __forceinline__ ushort4 pack4(float a, float b, float c, float d) {
    ushort4 u; u.x = f2bf(a); u.y = f2bf(b); u.z = f2bf(c); u.w = f2bf(d); return u;
}

// ---------------------------------------------------------------------------
// Wc[1024][512] bf16 = concat(Wf, Wg, Wh) rows, K-contiguous.
// ---------------------------------------------------------------------------
__global__ __launch_bounds__(256) void convert_w_kernel(
    const float* __restrict__ Wf, const float* __restrict__ Wg,
    const float* __restrict__ Wh, unsigned short* __restrict__ Wc)
{
    const int idx = blockIdx.x * 256 + threadIdx.x;
    const int o  = idx >> 7;
    const int c4 = (idx & 127) * 4;
    const float* src = (o < HCH)     ? (Wf + (size_t)o * CH + c4)
                     : (o < 2 * HCH) ? (Wg + (size_t)(o - HCH) * CH + c4)
                                     : (Wh + (size_t)(o - 2 * HCH) * CH + c4);
    float4 v = *(const float4*)src;
    *(ushort4*)&Wc[(size_t)o * CH + c4] = pack4(v.x, v.y, v.z, v.w);
}

// ---------------------------------------------------------------------------
// X' swizzle: x fp32 [b][512][4096] -> bf16 [b][cb=16][n=4096][co=32].
// ---------------------------------------------------------------------------
__global__ __launch_bounds__(256) void convert_x_kernel(
    const float* __restrict__ x, unsigned short* __restrict__ Xp)
{
    __shared__ unsigned short Lt[64][40];
    const int b  = blockIdx.z;
    const int cb = blockIdx.y;
    const int n0 = blockIdx.x * 64;
    const int t  = threadIdx.x;
    const int cr = t >> 4;
    const int f4 = t & 15;
    #pragma unroll
    for (int p = 0; p < 2; ++p) {
        const int c = p * 16 + cr;
        float4 v = *(const float4*)(x + ((size_t)b * CH + cb * 32 + c) * NPIX + n0 + f4 * 4);
        Lt[f4 * 4 + 0][c] = f2bf(v.x);
        Lt[f4 * 4 + 1][c] = f2bf(v.y);
        Lt[f4 * 4 + 2][c] = f2bf(v.z);
        Lt[f4 * 4 + 3][c] = f2bf(v.w);
    }
    __syncthreads();
    const int n  = t >> 2;
    const int ch = t & 3;
    uint4 u = *(const uint4*)&Lt[n][ch * 8];
    *(uint4*)&Xp[((size_t)b * 16 + cb) * (NPIX * 32) + (size_t)(n0 + n) * 32 + ch * 8] = u;
}

// ---------------------------------------------------------------------------
// proj F/G (unchanged)
// ---------------------------------------------------------------------------
__global__ __launch_bounds__(256, 2) void proj_fg_kernel(
    const unsigned short* __restrict__ Wc, const unsigned short* __restrict__ Xp,
    const float* __restrict__ bf, const float* __restrict__ bg,
    unsigned short* __restrict__ F, unsigned short* __restrict__ G)
{
    const int b  = blockIdx.z;
    const int n0 = blockIdx.x * 128;
    const int o0 = blockIdx.y * 128;
    const int t  = threadIdx.x;
    const int wave = t >> 6, lane = t & 63, quad = lane >> 4, l16 = lane & 15;
    const int ow = o0 + wave * 32;

    f32x4 acc[2][8];
    #pragma unroll
    for (int ms = 0; ms < 2; ++ms)
        #pragma unroll
        for (int ns = 0; ns < 8; ++ns) acc[ms][ns] = (f32x4){0.f, 0.f, 0.f, 0.f};

    const unsigned short* xb = Xp + (size_t)b * 16 * (NPIX * 32);
    for (int st = 0; st < 16; ++st) {
        bf16x8 a0 = *(const bf16x8*)&Wc[(size_t)(ow + l16) * CH + st * 32 + quad * 8];
        bf16x8 a1 = *(const bf16x8*)&Wc[(size_t)(ow + 16 + l16) * CH + st * 32 + quad * 8];
        const unsigned short* xs = xb + (size_t)st * (NPIX * 32) + quad * 8;
        #pragma unroll
        for (int ns = 0; ns < 8; ++ns) {
            bf16x8 bb = *(const bf16x8*)(xs + (size_t)(n0 + ns * 16 + l16) * 32);
            acc[0][ns] = MFMA16(a0, bb, acc[0][ns]);
            acc[1][ns] = MFMA16(a1, bb, acc[1][ns]);
        }
    }

    const int orow = quad * 4;
    #pragma unroll
    for (int ms = 0; ms < 2; ++ms) {
        const int ob = ow + ms * 16 + orow;
        float bias[4];
        #pragma unroll
        for (int r = 0; r < 4; ++r)
            bias[r] = (o0 < HCH) ? bf[ob + r] : bg[ob + r - HCH];
        #pragma unroll
        for (int ns = 0; ns < 8; ++ns) {
            const int n = n0 + ns * 16 + l16;
            ushort4 u = pack4(acc[ms][ns][0] + bias[0], acc[ms][ns][1] + bias[1],
                              acc[ms][ns][2] + bias[2], acc[ms][ns][3] + bias[3]);
            if (o0 < HCH) {
                *(ushort4*)&F[((size_t)b * NPIX + n) * HCH + ob] = u;
            } else {
                const int og = ob - HCH;
                const int cb = og >> 5, co = og & 31;
                *(ushort4*)&G[((size_t)b * 8 + cb) * (NPIX * 32) + (size_t)n * 32 + co] = u;
            }
        }
    }
}

// ---------------------------------------------------------------------------
// proj V (unchanged)
// ---------------------------------------------------------------------------
__global__ __launch_bounds__(256, 2) void proj_v_kernel(
    const unsigned short* __restrict__ Wc, const unsigned short* __restrict__ Xp,
    const float* __restrict__ bh, unsigned short* __restrict__ V)
{
    const int b  = blockIdx.z;
    const int c0 = blockIdx.x * 128;
    const int p0 = blockIdx.y * 128;
    const int t  = threadIdx.x;
    const int wave = t >> 6, lane = t & 63, quad = lane >> 4, l16 = lane & 15;
    const int pw = p0 + wave * 32;

    f32x4 acc[2][8];
    #pragma unroll
    for (int ms = 0; ms < 2; ++ms)
        #pragma unroll
        for (int ns = 0; ns < 8; ++ns) acc[ms][ns] = (f32x4){0.f, 0.f, 0.f, 0.f};

    const unsigned short* xb = Xp + (size_t)b * 16 * (NPIX * 32);
    for (int st = 0; st < 16; ++st) {
        const unsigned short* xs = xb + (size_t)st * (NPIX * 32) + quad * 8;
        bf16x8 a0 = *(const bf16x8*)(xs + (size_t)(pw + l16) * 32);
        bf16x8 a1 = *(const bf16x8*)(xs + (size_t)(pw + 16 + l16) * 32);
        #pragma unroll
        for (int ns = 0; ns < 8; ++ns) {
            bf16x8 bb = *(const bf16x8*)&Wc[(size_t)(2 * HCH + c0 + ns * 16 + l16) * CH + st * 32 + quad * 8];
            acc[0][ns] = MFMA16(a0, bb, acc[0][ns]);
            acc[1][ns] = MFMA16(a1, bb, acc[1][ns]);
        }
    }

    float biasv[8];
    #pragma unroll
    for (int ns = 0; ns < 8; ++ns) biasv[ns] = bh[c0 + ns * 16 + l16];

    const int kb = pw >> 5;
    const int ko0 = quad * 4;
    #pragma unroll
    for (int ms = 0; ms < 2; ++ms) {
        #pragma unroll
        for (int ns = 0; ns < 8; ++ns) {
            const int c = c0 + ns * 16 + l16;
            ushort4 u = pack4(acc[ms][ns][0] + biasv[ns], acc[ms][ns][1] + biasv[ns],
                              acc[ms][ns][2] + biasv[ns], acc[ms][ns][3] + biasv[ns]);
            *(ushort4*)&V[((size_t)b * 128 + kb) * (CH * 32) + (size_t)c * 32 + ms * 16 + ko0] = u;
        }
    }
}

// ---------------------------------------------------------------------------
// score: QK^T computed ONCE. S -> exp2 -> bf16 P written to HBM (layout
// [b][kb=128][q=4096][ko=32]), rowl += rowsums. (unchanged from round 3)
// ---------------------------------------------------------------------------
__global__ __launch_bounds__(512, 4) void score_kernel(
    const unsigned short* __restrict__ F, const unsigned short* __restrict__ G,
    unsigned short* __restrict__ P, float* __restrict__ rowl)
{
    const int blk = blockIdx.x;
    const int xcd = blk & 7;
    const int b   = xcd >> 1;
    const int kh  = xcd & 1;
    const int q0  = (blk >> 3) * 64;
    const int t    = threadIdx.x;
    const int wave = t >> 6, lane = t & 63, quad = lane >> 4, l16 = lane & 15;
    const int qh = wave >> 2, kw = wave & 3;

    bf16x8 af[2][8];
    #pragma unroll
    for (int qs = 0; qs < 2; ++qs)
        #pragma unroll
        for (int st = 0; st < 8; ++st)
            af[qs][st] = *(const bf16x8*)&F[((size_t)b * NPIX + q0 + qh * 32 + qs * 16 + l16) * HCH + st * 32 + quad * 8];

    float ls[2][4];
    #pragma unroll
    for (int qs = 0; qs < 2; ++qs)
        #pragma unroll
        for (int r = 0; r < 4; ++r) ls[qs][r] = 0.f;

    const unsigned short* Gb = G + (size_t)b * 8 * (NPIX * 32);
    unsigned short* Pbase = P + (size_t)b * 128 * (NPIX * 32)
                              + ((size_t)(q0 + qh * 32 + quad * 4)) * 32 + l16;

    const int kbeg = kh * 2048, kend = kbeg + 2048;
    for (int k0 = kbeg; k0 < kend; k0 += 128) {
        const int kk = k0 + kw * 32;
        f32x4 s[2][2];
        #pragma unroll
        for (int qs = 0; qs < 2; ++qs)
            #pragma unroll
            for (int ks = 0; ks < 2; ++ks) s[qs][ks] = (f32x4){0.f, 0.f, 0.f, 0.f};
        #pragma unroll
        for (int st = 0; st < 8; ++st) {
            const unsigned short* gs = Gb + (size_t)st * (NPIX * 32) + quad * 8;
            bf16x8 b0 = *(const bf16x8*)(gs + (size_t)(kk + l16) * 32);
            bf16x8 b1 = *(const bf16x8*)(gs + (size_t)(kk + 16 + l16) * 32);
            s[0][0] = MFMA16(af[0][st], b0, s[0][0]);
            s[1][0] = MFMA16(af[1][st], b0, s[1][0]);
            s[0][1] = MFMA16(af[0][st], b1, s[0][1]);
            s[1][1] = MFMA16(af[1][st], b1, s[1][1]);
        }

        unsigned short* pw = Pbase + (size_t)(kk >> 5) * (NPIX * 32);
        #pragma unroll
        for (int qs = 0; qs < 2; ++qs)
            #pragma unroll
            for (int ks = 0; ks < 2; ++ks)
                #pragma unroll
                for (int r = 0; r < 4; ++r) {
                    float e = exp2f(L2E * s[qs][ks][r]);
                    pw[qs * 512 + r * 32 + ks * 16] = f2bf(e);
                    ls[qs][r] += e;
                }
    }

    #pragma unroll
    for (int d = 1; d < 16; d <<= 1)
        #pragma unroll
        for (int qs = 0; qs < 2; ++qs)
            #pragma unroll
            for (int r = 0; r < 4; ++r) ls[qs][r] += __shfl_xor(ls[qs][r], d, 64);

    if (l16 == 0) {
        #pragma unroll
        for (int qs = 0; qs < 2; ++qs)
            #pragma unroll
            for (int r = 0; r < 4; ++r)
                atomicAdd(&rowl[(size_t)b * NPIX + q0 + qh * 32 + qs * 16 + quad * 4 + r], ls[qs][r]);
    }
}

// ---------------------------------------------------------------------------
// pv: O[q][c] = P(4096x4096) x V(4096x512), linv in epilogue.
// Round-4 change: 1024-thread blocks, 16 waves = 2 k-halves x 8 wave-tiles.
// Grid stays 512 = 2 blocks/CU -> 32 waves/CU (occupancy cap; was 16,
// grid-limited, latency-bound at MfmaUtil 13%). Inner loop body UNCHANGED
// (round-1 lesson: total regs must stay <=64 for 8 waves/SIMD; no extra
// unroll/prefetch). k-halves combine via one 64KB XOR-swizzled LDS
// exchange + single barrier; no atomics, no extra workspace.
// ---------------------------------------------------------------------------
__global__ __launch_bounds__(1024, 2) void pv_kernel(
    const unsigned short* __restrict__ P, const unsigned short* __restrict__ V,
    const float* __restrict__ rowl, float* __restrict__ outres)
{
    __shared__ float Ored[512 * 32];       // 64 KB exchange buffer
    const int blk = blockIdx.x;
    const int xcd = blk & 7;
    const int b   = xcd >> 1;
    const int ch  = xcd & 1;
    const int q0  = (blk >> 3) * 64;
    const int t    = threadIdx.x;
    const int kh   = t >> 9;               // k-half: 0 -> kb 0..63, 1 -> 64..127
    const int i    = t & 511;              // index within half
    const int wave = i >> 6, lane = t & 63, quad = lane >> 4, l16 = lane & 15;
    const int qw = wave >> 2;              // 0..1 -> 32q
    const int cw = wave & 3;               // 0..3 -> 64c
    const int cbase = ch * 256 + cw * 64;

    f32x4 O[2][4];
    #pragma unroll
    for (int qs = 0; qs < 2; ++qs)
        #pragma unroll
        for (int ct = 0; ct < 4; ++ct) O[qs][ct] = (f32x4){0.f, 0.f, 0.f, 0.f};

    const unsigned short* pa = P + ((size_t)(b * 128 + kh * 64) * NPIX + (q0 + qw * 32 + l16)) * 32 + quad * 8;
    const unsigned short* vb = V + ((size_t)(b * 128 + kh * 64) * CH + (cbase + l16)) * 32 + quad * 8;

    #pragma unroll 2
    for (int kb = 0; kb < 64; ++kb) {
        bf16x8 a0 = *(const bf16x8*)(pa);
        bf16x8 a1 = *(const bf16x8*)(pa + 512);
        bf16x8 v0 = *(const bf16x8*)(vb);
        bf16x8 v1 = *(const bf16x8*)(vb + 512);
        bf16x8 v2 = *(const bf16x8*)(vb + 1024);
        bf16x8 v3 = *(const bf16x8*)(vb + 1536);
        O[0][0] = MFMA16(a0, v0, O[0][0]);
        O[1][0] = MFMA16(a1, v0, O[1][0]);
        O[0][1] = MFMA16(a0, v1, O[0][1]);
        O[1][1] = MFMA16(a1, v1, O[1][1]);
        O[0][2] = MFMA16(a0, v2, O[0][2]);
        O[1][2] = MFMA16(a1, v2, O[1][2]);
        O[0][3] = MFMA16(a0, v3, O[0][3]);
        O[1][3] = MFMA16(a1, v3, O[1][3]);
        pa += (size_t)NPIX * 32;
        vb += (size_t)CH * 32;
    }

    // upper k-half publishes partials: slot i, f32x4 j at byte
    // i*128 + (j*16 ^ ((i&7)<<4))  -- conflict-free (8 lanes span 32 banks)
    if (kh) {
        char* lb = (char*)Ored + (size_t)i * 128;
        #pragma unroll
        for (int qs = 0; qs < 2; ++qs)
            #pragma unroll
            for (int ct = 0; ct < 4; ++ct) {
                const int j = qs * 4 + ct;
                *(f32x4*)(lb + ((j * 16) ^ ((i & 7) << 4))) = O[qs][ct];
            }
    }
    __syncthreads();
    if (!kh) {
        float lr[2][4];
        #pragma unroll
        for (int qs = 0; qs < 2; ++qs)
            #pragma unroll
            for (int r = 0; r < 4; ++r)
                lr[qs][r] = 1.0f / rowl[(size_t)b * NPIX + q0 + qw * 32 + qs * 16 + quad * 4 + r];

        const char* lb = (const char*)Ored + (size_t)i * 128;
        #pragma unroll
        for (int qs = 0; qs < 2; ++qs) {
            #pragma unroll
            for (int ct = 0; ct < 4; ++ct) {
                const int j = qs * 4 + ct;
                f32x4 o2 = *(const f32x4*)(lb + ((j * 16) ^ ((i & 7) << 4)));
                f32x4 o = O[qs][ct] + o2;
                o[0] *= lr[qs][0]; o[1] *= lr[qs][1]; o[2] *= lr[qs][2]; o[3] *= lr[qs][3];
                const int c = cbase + ct * 16 + l16;
                *(f32x4*)&outres[((size_t)b * CH + c) * NPIX + q0 + qw * 32 + qs * 16 + quad * 4] = o;
            }
        }
    }
}

// ---------------------------------------------------------------------------
// colsum: attnacc[b][k] = sum_q P[b][q][k] * linv[q]. (unchanged)
// ---------------------------------------------------------------------------
__global__ __launch_bounds__(256) void colsum_kernel(
    const unsigned short* __restrict__ P, const float* __restrict__ rowl,
    float* __restrict__ attnacc)
{
    __shared__ float CS[16][32];
    const int blk = blockIdx.x;            // b*128 + kb
    const int b  = blk >> 7;
    const int kb = blk & 127;
    const int t  = threadIdx.x;
    const int ko2 = t & 15;
    const int qr  = t >> 4;
    const unsigned short* Pb = P + (size_t)(b * 128 + kb) * (NPIX * 32);
    const float* rl = rowl + (size_t)b * NPIX;

    float a0 = 0.f, a1 = 0.f;
    for (int q = qr; q < NPIX; q += 16) {
        unsigned int u = *(const unsigned int*)(Pb + (size_t)q * 32 + ko2 * 2);
        float li = 1.0f / rl[q];
        a0 += __uint_as_float(u << 16) * li;
        a1 += __uint_as_float(u & 0xFFFF0000u) * li;
    }
    CS[qr][ko2 * 2]     = a0;
    CS[qr][ko2 * 2 + 1] = a1;
    __syncthreads();
    if (t < 32) {
        float s = 0.f;
        #pragma unroll
        for (int i = 0; i < 16; ++i) s += CS[i][t];
        attnacc[(size_t)b * NPIX + kb * 32 + t] = s;
    }
}

// ---------------------------------------------------------------------------
// FALLBACK path (used only if ws_size too small for P): round-2 stats+apply.
// ---------------------------------------------------------------------------
__global__ __launch_bounds__(512, 4) void stats_kernel(
    const unsigned short* __restrict__ F, const unsigned short* __restrict__ G,
    float* __restrict__ rowl)
{
    const int blk = blockIdx.x;
    const int xcd = blk & 7;
    const int b   = xcd >> 1;
    const int kh  = xcd & 1;
    const int q0  = (blk >> 3) * 64;
    const int t    = threadIdx.x;
    const int wave = t >> 6, lane = t & 63, quad = lane >> 4, l16 = lane & 15;
    const int qh = wave >> 2, kw = wave & 3;

    bf16x8 af[2][8];
    #pragma unroll
    for (int qs = 0; qs < 2; ++qs)
        #pragma unroll
        for (int st = 0; st < 8; ++st)
            af[qs][st] = *(const bf16x8*)&F[((size_t)b * NPIX + q0 + qh * 32 + qs * 16 + l16) * HCH + st * 32 + quad * 8];

    float ls[2][4];
    #pragma unroll
    for (int qs = 0; qs < 2; ++qs)
        #pragma unroll
        for (int r = 0; r < 4; ++r) ls[qs][r] = 0.f;

    const unsigned short* Gb = G + (size_t)b * 8 * (NPIX * 32);
    const int kbeg = kh * 2048, kend = kbeg + 2048;
    for (int k0 = kbeg; k0 < kend; k0 += 128) {
        const int kk = k0 + kw * 32;
        f32x4 s[2][2];
        #pragma unroll
        for (int qs = 0; qs < 2; ++qs)
            #pragma unroll
            for (int ks = 0; ks < 2; ++ks) s[qs][ks] = (f32x4){0.f, 0.f, 0.f, 0.f};
        #pragma unroll
        for (int st = 0; st < 8; ++st) {
            const unsigned short* gs = Gb + (size_t)st * (NPIX * 32) + quad * 8;
            bf16x8 b0 = *(const bf16x8*)(gs + (size_t)(kk + l16) * 32);
            bf16x8 b1 = *(const bf16x8*)(gs + (size_t)(kk + 16 + l16) * 32);
            s[0][0] = MFMA16(af[0][st], b0, s[0][0]);
            s[1][0] = MFMA16(af[1][st], b0, s[1][0]);
            s[0][1] = MFMA16(af[0][st], b1, s[0][1]);
            s[1][1] = MFMA16(af[1][st], b1, s[1][1]);
        }
        #pragma unroll
        for (int qs = 0; qs < 2; ++qs)
            #pragma unroll
            for (int r = 0; r < 4; ++r)
                ls[qs][r] += exp2f(L2E * s[qs][0][r]) + exp2f(L2E * s[qs][1][r]);
    }

    #pragma unroll
    for (int d = 1; d < 16; d <<= 1)
        #pragma unroll
        for (int qs = 0; qs < 2; ++qs)
            #pragma unroll
            for (int r = 0; r < 4; ++r) ls[qs][r] += __shfl_xor(ls[qs][r], d, 64);

    if (l16 == 0) {
        #pragma unroll
        for (int qs = 0; qs < 2; ++qs)
            #pragma unroll
            for (int r = 0; r < 4; ++r)
                atomicAdd(&rowl[(size_t)b * NPIX + q0 + qh * 32 + qs * 16 + quad * 4 + r], ls[qs][r]);
    }
}

__global__ __launch_bounds__(512, 4) void apply_kernel(
    const unsigned short* __restrict__ F, const unsigned short* __restrict__ G,
    const unsigned short* __restrict__ V, const float* __restrict__ rowl,
    float* __restrict__ outres, float* __restrict__ attnacc)
{
    __shared__ unsigned short Pl[2][32][136];
    const int blk = blockIdx.x;
    const int xcd = blk & 7;
    const int b   = xcd >> 1;
    const int ch  = xcd & 1;
    const int q0  = (blk >> 3) * 32;
    const int t    = threadIdx.x;
    const int wave = t >> 6, lane = t & 63, quad = lane >> 4, l16 = lane & 15;
    const int cw = ch * 256 + wave * 32;

    float linv[2][4];
    #pragma unroll
    for (int qs = 0; qs < 2; ++qs)
        #pragma unroll
        for (int r = 0; r < 4; ++r)
            linv[qs][r] = 1.0f / rowl[(size_t)b * NPIX + q0 + qs * 16 + quad * 4 + r];

    f32x4 O[2][2];
    #pragma unroll
    for (int qs = 0; qs < 2; ++qs)
        #pragma unroll
        for (int ct = 0; ct < 2; ++ct) O[qs][ct] = (f32x4){0.f, 0.f, 0.f, 0.f};

    const unsigned short* Gb = G + (size_t)b * 8 * (NPIX * 32);
    const unsigned short* Vb = V + (size_t)b * 128 * (CH * 32);
    const unsigned short* Fq = F + ((size_t)b * NPIX + q0) * HCH;

    int buf = 0;
    for (int k0 = 0; k0 < NPIX; k0 += 128) {
        const int kk = k0 + wave * 16;
        f32x4 s[2];
        s[0] = (f32x4){0.f, 0.f, 0.f, 0.f};
        s[1] = (f32x4){0.f, 0.f, 0.f, 0.f};
        #pragma unroll
        for (int st = 0; st < 8; ++st) {
            bf16x8 a0 = *(const bf16x8*)&Fq[(size_t)l16 * HCH + st * 32 + quad * 8];
            bf16x8 a1 = *(const bf16x8*)&Fq[(size_t)(16 + l16) * HCH + st * 32 + quad * 8];
            bf16x8 bg = *(const bf16x8*)(Gb + (size_t)st * (NPIX * 32) + (size_t)(kk + l16) * 32 + quad * 8);
            s[0] = MFMA16(a0, bg, s[0]);
            s[1] = MFMA16(a1, bg, s[1]);
        }

        float p[2][4];
        #pragma unroll
        for (int qs = 0; qs < 2; ++qs)
            #pragma unroll
            for (int r = 0; r < 4; ++r)
                p[qs][r] = exp2f(L2E * s[qs][r]) * linv[qs][r];

        #pragma unroll
        for (int qs = 0; qs < 2; ++qs)
            #pragma unroll
            for (int r = 0; r < 4; ++r)
                Pl[buf][qs * 16 + quad * 4 + r][wave * 16 + l16] = f2bf(p[qs][r]);

        if (ch == 0) {
            float cs = p[0][0] + p[0][1] + p[0][2] + p[0][3]
                     + p[1][0] + p[1][1] + p[1][2] + p[1][3];
            cs += __shfl_xor(cs, 16, 64);
            cs += __shfl_xor(cs, 32, 64);
            if (quad == 0)
                atomicAdd(&attnacc[(size_t)b * NPIX + kk + l16], cs);
        }

        __syncthreads();

        #pragma unroll
        for (int ks = 0; ks < 4; ++ks) {
            bf16x8 pa0 = *(const bf16x8*)&Pl[buf][l16][ks * 32 + quad * 8];
            bf16x8 pa1 = *(const bf16x8*)&Pl[buf][16 + l16][ks * 32 + quad * 8];
            const unsigned short* vs = Vb + ((size_t)(k0 >> 5) + ks) * (CH * 32) + quad * 8;
            #pragma unroll
            for (int ct = 0; ct < 2; ++ct) {
                bf16x8 vv = *(const bf16x8*)(vs + (size_t)(cw + ct * 16 + l16) * 32);
                O[0][ct] = MFMA16(pa0, vv, O[0][ct]);
                O[1][ct] = MFMA16(pa1, vv, O[1][ct]);
            }
        }
        buf ^= 1;
    }

    #pragma unroll
    for (int qs = 0; qs < 2; ++qs) {
        #pragma unroll
        for (int ct = 0; ct < 2; ++ct) {
            const int c = cw + ct * 16 + l16;
            *(f32x4*)&outres[((size_t)b * CH + c) * NPIX + q0 + qs * 16 + quad * 4] = O[qs][ct];
        }
    }
}

__global__ __launch_bounds__(256) void attn_fin_kernel(
    const float* __restrict__ acc, float* __restrict__ outa)
{
    const int i = blockIdx.x * 256 + threadIdx.x;
    if (i < BATCH * NPIX) outa[i] = acc[i] * (1.0f / (float)NPIX);
}

extern "C" void kernel_launch(void* const* d_in, const int* in_sizes, int n_in,
                              void* d_out, int out_size, void* d_ws, size_t ws_size,
                              hipStream_t stream)
{
    (void)in_sizes; (void)n_in; (void)out_size;
    const float* x  = (const float*)d_in[0];
    const float* Wf = (const float*)d_in[1];
    const float* bf = (const float*)d_in[2];
    const float* Wg = (const float*)d_in[3];
    const float* bg = (const float*)d_in[4];
    const float* Wh = (const float*)d_in[5];
    const float* bh = (const float*)d_in[6];
    float* out = (float*)d_out;

    const size_t P_ELEMS  = (size_t)BATCH * 128 * NPIX * 32;   // 67,108,864
    const size_t XP_ELEMS = (size_t)BATCH * 16 * NPIX * 32;    //  8,388,608
    const size_t F_ELEMS  = (size_t)BATCH * NPIX * HCH;        //  4,194,304
    const size_t V_ELEMS  = (size_t)BATCH * 128 * CH * 32;     //  8,388,608
    const size_t NEED = (P_ELEMS + 2 * F_ELEMS + V_ELEMS) * 2
                      + (size_t)2 * BATCH * NPIX * 4;          // ~167.9 MB

    if (ws_size >= NEED) {
        // ---- materialized-P path. P overlays Xp+Wc (dead before score).
        unsigned short* P  = (unsigned short*)d_ws;
        unsigned short* Xp = P;
        unsigned short* Wc = P + XP_ELEMS;
        unsigned short* F  = P + P_ELEMS;
        unsigned short* G  = F + F_ELEMS;
        unsigned short* V  = G + F_ELEMS;
        float* rowl    = (float*)(V + V_ELEMS);
        float* attnacc = rowl + (size_t)BATCH * NPIX;

        hipMemsetAsync(rowl, 0, (size_t)BATCH * NPIX * sizeof(float), stream);

        convert_w_kernel<<<512, 256, 0, stream>>>(Wf, Wg, Wh, Wc);
        convert_x_kernel<<<dim3(NPIX / 64, 16, BATCH), 256, 0, stream>>>(x, Xp);

        proj_fg_kernel<<<dim3(NPIX / 128, 4, BATCH), 256, 0, stream>>>(Wc, Xp, bf, bg, F, G);
        proj_v_kernel<<<dim3(4, NPIX / 128, BATCH), 256, 0, stream>>>(Wc, Xp, bh, V);

        score_kernel<<<512, 512, 0, stream>>>(F, G, P, rowl);
        pv_kernel<<<512, 1024, 0, stream>>>(P, V, rowl, out);
        colsum_kernel<<<512, 256, 0, stream>>>(P, rowl, attnacc);

        attn_fin_kernel<<<BATCH * NPIX / 256, 256, 0, stream>>>(
            attnacc, out + (size_t)BATCH * CH * NPIX);
    } else {
        // ---- fallback: round-2 layout & kernels.
        unsigned short* Xp = (unsigned short*)d_ws;
        unsigned short* Wc = Xp + XP_ELEMS;
        unsigned short* F  = Wc + (size_t)1024 * CH;
        unsigned short* G  = F + F_ELEMS;
        unsigned short* V  = G + F_ELEMS;
        float* rowl    = (float*)(V + V_ELEMS);
        float* attnacc = rowl + (size_t)BATCH * NPIX;

        hipMemsetAsync(rowl, 0, (size_t)2 * BATCH * NPIX * sizeof(float), stream);

        convert_w_kernel<<<512, 256, 0, stream>>>(Wf, Wg, Wh, Wc);
        convert_x_kernel<<<dim3(NPIX / 64, 16, BATCH), 256, 0, stream>>>(x, Xp);

        proj_fg_kernel<<<dim3(NPIX / 128, 4, BATCH), 256, 0, stream>>>(Wc, Xp, bf, bg, F, G);
        proj_v_kernel<<<dim3(4, NPIX / 128, BATCH), 256, 0, stream>>>(Wc, Xp, bh, V);

        stats_kernel<<<512, 512, 0, stream>>>(F, G, rowl);
        apply_kernel<<<1024, 512, 0, stream>>>(F, G, V, rowl, out, attnacc);

        attn_fin_kernel<<<BATCH * NPIX / 256, 256, 0, stream>>>(
            attnacc, out + (size_t)BATCH * CH * NPIX);
    }
}

// Round 6
// 463.142 us; speedup vs baseline: 1.5867x; 1.1436x over previous
//
#include <hip/hip_runtime.h>
#include <cmath>

#define BATCH 4
#define CH    512
#define HCH   256
#define NPIX  4096
#define L2E   1.44269504088896340736f

typedef __attribute__((ext_vector_type(8))) short bf16x8;
typedef __attribute__((ext_vector_type(4))) float f32x4;

#define MFMA16(a, b, c) __builtin_amdgcn_mfma_f32_16x16x32_bf16((a), (b), (c), 0, 0, 0)

__device__ __forceinline__ unsigned short f2bf(float f) {
    unsigned int u = __float_as_uint(f);
    return (unsigned short)((u + 0x7fffu + ((u >> 16) & 1u)) >> 16);
}
__device__ __forceinline__ ushort4 pack4(float a, float b, float c, float d) {
    ushort4 u; u.x = f2bf(a); u.y = f2bf(b); u.z = f2bf(c); u.w = f2bf(d); return u;
}
// async global->LDS, 16B per lane; LDS dest is wave-uniform base + lane*16.
__device__ __forceinline__ void gload16(const unsigned short* g, unsigned short* l) {
    __builtin_amdgcn_global_load_lds(
        (const __attribute__((address_space(1))) unsigned int*)g,
        (__attribute__((address_space(3))) unsigned int*)l, 16, 0, 0);
}

// ---------------------------------------------------------------------------
// Wc[1024][512] bf16 = concat(Wf, Wg, Wh) rows, K-contiguous.
// ---------------------------------------------------------------------------
__global__ __launch_bounds__(256) void convert_w_kernel(
    const float* __restrict__ Wf, const float* __restrict__ Wg,
    const float* __restrict__ Wh, unsigned short* __restrict__ Wc)
{
    const int idx = blockIdx.x * 256 + threadIdx.x;
    const int o  = idx >> 7;
    const int c4 = (idx & 127) * 4;
    const float* src = (o < HCH)     ? (Wf + (size_t)o * CH + c4)
                     : (o < 2 * HCH) ? (Wg + (size_t)(o - HCH) * CH + c4)
                                     : (Wh + (size_t)(o - 2 * HCH) * CH + c4);
    float4 v = *(const float4*)src;
    *(ushort4*)&Wc[(size_t)o * CH + c4] = pack4(v.x, v.y, v.z, v.w);
}

// ---------------------------------------------------------------------------
// X' swizzle: x fp32 [b][512][4096] -> bf16 [b][cb=16][n=4096][co=32].
// ---------------------------------------------------------------------------
__global__ __launch_bounds__(256) void convert_x_kernel(
    const float* __restrict__ x, unsigned short* __restrict__ Xp)
{
    __shared__ unsigned short Lt[64][40];
    const int b  = blockIdx.z;
    const int cb = blockIdx.y;
    const int n0 = blockIdx.x * 64;
    const int t  = threadIdx.x;
    const int cr = t >> 4;
    const int f4 = t & 15;
    #pragma unroll
    for (int p = 0; p < 2; ++p) {
        const int c = p * 16 + cr;
        float4 v = *(const float4*)(x + ((size_t)b * CH + cb * 32 + c) * NPIX + n0 + f4 * 4);
        Lt[f4 * 4 + 0][c] = f2bf(v.x);
        Lt[f4 * 4 + 1][c] = f2bf(v.y);
        Lt[f4 * 4 + 2][c] = f2bf(v.z);
        Lt[f4 * 4 + 3][c] = f2bf(v.w);
    }
    __syncthreads();
    const int n  = t >> 2;
    const int ch = t & 3;
    uint4 u = *(const uint4*)&Lt[n][ch * 8];
    *(uint4*)&Xp[((size_t)b * 16 + cb) * (NPIX * 32) + (size_t)(n0 + n) * 32 + ch * 8] = u;
}

// ---------------------------------------------------------------------------
// proj F/G (unchanged)
// ---------------------------------------------------------------------------
__global__ __launch_bounds__(256, 2) void proj_fg_kernel(
    const unsigned short* __restrict__ Wc, const unsigned short* __restrict__ Xp,
    const float* __restrict__ bf, const float* __restrict__ bg,
    unsigned short* __restrict__ F, unsigned short* __restrict__ G)
{
    const int b  = blockIdx.z;
    const int n0 = blockIdx.x * 128;
    const int o0 = blockIdx.y * 128;
    const int t  = threadIdx.x;
    const int wave = t >> 6, lane = t & 63, quad = lane >> 4, l16 = lane & 15;
    const int ow = o0 + wave * 32;

    f32x4 acc[2][8];
    #pragma unroll
    for (int ms = 0; ms < 2; ++ms)
        #pragma unroll
        for (int ns = 0; ns < 8; ++ns) acc[ms][ns] = (f32x4){0.f, 0.f, 0.f, 0.f};

    const unsigned short* xb = Xp + (size_t)b * 16 * (NPIX * 32);
    for (int st = 0; st < 16; ++st) {
        bf16x8 a0 = *(const bf16x8*)&Wc[(size_t)(ow + l16) * CH + st * 32 + quad * 8];
        bf16x8 a1 = *(const bf16x8*)&Wc[(size_t)(ow + 16 + l16) * CH + st * 32 + quad * 8];
        const unsigned short* xs = xb + (size_t)st * (NPIX * 32) + quad * 8;
        #pragma unroll
        for (int ns = 0; ns < 8; ++ns) {
            bf16x8 bb = *(const bf16x8*)(xs + (size_t)(n0 + ns * 16 + l16) * 32);
            acc[0][ns] = MFMA16(a0, bb, acc[0][ns]);
            acc[1][ns] = MFMA16(a1, bb, acc[1][ns]);
        }
    }

    const int orow = quad * 4;
    #pragma unroll
    for (int ms = 0; ms < 2; ++ms) {
        const int ob = ow + ms * 16 + orow;
        float bias[4];
        #pragma unroll
        for (int r = 0; r < 4; ++r)
            bias[r] = (o0 < HCH) ? bf[ob + r] : bg[ob + r - HCH];
        #pragma unroll
        for (int ns = 0; ns < 8; ++ns) {
            const int n = n0 + ns * 16 + l16;
            ushort4 u = pack4(acc[ms][ns][0] + bias[0], acc[ms][ns][1] + bias[1],
                              acc[ms][ns][2] + bias[2], acc[ms][ns][3] + bias[3]);
            if (o0 < HCH) {
                *(ushort4*)&F[((size_t)b * NPIX + n) * HCH + ob] = u;
            } else {
                const int og = ob - HCH;
                const int cb = og >> 5, co = og & 31;
                *(ushort4*)&G[((size_t)b * 8 + cb) * (NPIX * 32) + (size_t)n * 32 + co] = u;
            }
        }
    }
}

// ---------------------------------------------------------------------------
// proj V: output layout [b][kb=128][c=512][ko=32], stored in the XOR-swizzled
// bank image (element ^= ((c&7)<<3), ushort units), so pv can global_load_lds
// it LINEARLY and ds_read conflict-free (rule: swizzle both sides or neither).
// ---------------------------------------------------------------------------
__global__ __launch_bounds__(256, 2) void proj_v_kernel(
    const unsigned short* __restrict__ Wc, const unsigned short* __restrict__ Xp,
    const float* __restrict__ bh, unsigned short* __restrict__ V)
{
    const int b  = blockIdx.z;
    const int c0 = blockIdx.x * 128;
    const int p0 = blockIdx.y * 128;
    const int t  = threadIdx.x;
    const int wave = t >> 6, lane = t & 63, quad = lane >> 4, l16 = lane & 15;
    const int pw = p0 + wave * 32;

    f32x4 acc[2][8];
    #pragma unroll
    for (int ms = 0; ms < 2; ++ms)
        #pragma unroll
        for (int ns = 0; ns < 8; ++ns) acc[ms][ns] = (f32x4){0.f, 0.f, 0.f, 0.f};

    const unsigned short* xb = Xp + (size_t)b * 16 * (NPIX * 32);
    for (int st = 0; st < 16; ++st) {
        const unsigned short* xs = xb + (size_t)st * (NPIX * 32) + quad * 8;
        bf16x8 a0 = *(const bf16x8*)(xs + (size_t)(pw + l16) * 32);
        bf16x8 a1 = *(const bf16x8*)(xs + (size_t)(pw + 16 + l16) * 32);
        #pragma unroll
        for (int ns = 0; ns < 8; ++ns) {
            bf16x8 bb = *(const bf16x8*)&Wc[(size_t)(2 * HCH + c0 + ns * 16 + l16) * CH + st * 32 + quad * 8];
            acc[0][ns] = MFMA16(a0, bb, acc[0][ns]);
            acc[1][ns] = MFMA16(a1, bb, acc[1][ns]);
        }
    }

    float biasv[8];
    #pragma unroll
    for (int ns = 0; ns < 8; ++ns) biasv[ns] = bh[c0 + ns * 16 + l16];

    const int kb = pw >> 5;
    const int ko0 = quad * 4;
    const int cx = (l16 & 7) << 3;   // c&7 == l16&7 (c = c0+ns*16+l16), ushort units
    #pragma unroll
    for (int ms = 0; ms < 2; ++ms) {
        #pragma unroll
        for (int ns = 0; ns < 8; ++ns) {
            const int c = c0 + ns * 16 + l16;
            ushort4 u = pack4(acc[ms][ns][0] + biasv[ns], acc[ms][ns][1] + biasv[ns],
                              acc[ms][ns][2] + biasv[ns], acc[ms][ns][3] + biasv[ns]);
            const int el = (c * 32 + ms * 16 + ko0) ^ cx;   // swizzled image
            *(ushort4*)&V[((size_t)b * 128 + kb) * (CH * 32) + el] = u;
        }
    }
}

// ---------------------------------------------------------------------------
// score: QK^T once; P = exp2(S) bf16 written to HBM in layout
// [b][kb=128][q=4096][ko=32] in the XOR-swizzled image
// (el ^= ((q&7)<<3), ushort units). rowl += rowsums.
// ---------------------------------------------------------------------------
__global__ __launch_bounds__(512, 4) void score_kernel(
    const unsigned short* __restrict__ F, const unsigned short* __restrict__ G,
    unsigned short* __restrict__ P, float* __restrict__ rowl)
{
    const int blk = blockIdx.x;
    const int xcd = blk & 7;
    const int b   = xcd >> 1;
    const int kh  = xcd & 1;
    const int q0  = (blk >> 3) * 64;
    const int t    = threadIdx.x;
    const int wave = t >> 6, lane = t & 63, quad = lane >> 4, l16 = lane & 15;
    const int qh = wave >> 2, kw = wave & 3;

    bf16x8 af[2][8];
    #pragma unroll
    for (int qs = 0; qs < 2; ++qs)
        #pragma unroll
        for (int st = 0; st < 8; ++st)
            af[qs][st] = *(const bf16x8*)&F[((size_t)b * NPIX + q0 + qh * 32 + qs * 16 + l16) * HCH + st * 32 + quad * 8];

    float ls[2][4];
    #pragma unroll
    for (int qs = 0; qs < 2; ++qs)
        #pragma unroll
        for (int r = 0; r < 4; ++r) ls[qs][r] = 0.f;

    const unsigned short* Gb = G + (size_t)b * 8 * (NPIX * 32);
    // base WITHOUT quad/l16 terms; per-store element index carries the swizzle
    unsigned short* Pb2 = P + (size_t)b * 128 * (NPIX * 32) + (size_t)(q0 + qh * 32) * 32;
    const int qx = (quad & 1) * 4;   // (q&7) = qx + r for row q = ...+quad*4+r

    const int kbeg = kh * 2048, kend = kbeg + 2048;
    for (int k0 = kbeg; k0 < kend; k0 += 128) {
        const int kk = k0 + kw * 32;
        f32x4 s[2][2];
        #pragma unroll
        for (int qs = 0; qs < 2; ++qs)
            #pragma unroll
            for (int ks = 0; ks < 2; ++ks) s[qs][ks] = (f32x4){0.f, 0.f, 0.f, 0.f};
        #pragma unroll
        for (int st = 0; st < 8; ++st) {
            const unsigned short* gs = Gb + (size_t)st * (NPIX * 32) + quad * 8;
            bf16x8 b0 = *(const bf16x8*)(gs + (size_t)(kk + l16) * 32);
            bf16x8 b1 = *(const bf16x8*)(gs + (size_t)(kk + 16 + l16) * 32);
            s[0][0] = MFMA16(af[0][st], b0, s[0][0]);
            s[1][0] = MFMA16(af[1][st], b0, s[1][0]);
            s[0][1] = MFMA16(af[0][st], b1, s[0][1]);
            s[1][1] = MFMA16(af[1][st], b1, s[1][1]);
        }

        unsigned short* pw = Pb2 + (size_t)(kk >> 5) * (NPIX * 32);
        #pragma unroll
        for (int qs = 0; qs < 2; ++qs)
            #pragma unroll
            for (int ks = 0; ks < 2; ++ks)
                #pragma unroll
                for (int r = 0; r < 4; ++r) {
                    float e = exp2f(L2E * s[qs][ks][r]);
                    const int el = ((qs * 16 + quad * 4 + r) * 32 + ks * 16 + l16)
                                   ^ ((qx + r) << 3);
                    pw[el] = f2bf(e);
                    ls[qs][r] += e;
                }
    }

    #pragma unroll
    for (int d = 1; d < 16; d <<= 1)
        #pragma unroll
        for (int qs = 0; qs < 2; ++qs)
            #pragma unroll
            for (int r = 0; r < 4; ++r) ls[qs][r] += __shfl_xor(ls[qs][r], d, 64);

    if (l16 == 0) {
        #pragma unroll
        for (int qs = 0; qs < 2; ++qs)
            #pragma unroll
            for (int r = 0; r < 4; ++r)
                atomicAdd(&rowl[(size_t)b * NPIX + q0 + qh * 32 + qs * 16 + quad * 4 + r], ls[qs][r]);
    }
}

// ---------------------------------------------------------------------------
// pv v3: m97-style LDS-double-buffered GEMM. Block 64q x 256c (ch half),
// 512 thr (8 waves = 2qw x 4cw, wave 32q x 64c). BK=32 (one kb): stage
// P 4KB + V 16KB per step via global_load_lds (deep in-flight prefetch,
// zero VGPR cost -- the round-4 bottleneck), ONE barrier per step.
// Global P/V are stored pre-swizzled, LDS copy is linear, ds_reads apply
// the same XOR -> conflict-free. LDS 40KB -> 2 blocks/CU.
// ---------------------------------------------------------------------------
__global__ __launch_bounds__(512, 4) void pv_kernel(
    const unsigned short* __restrict__ P, const unsigned short* __restrict__ V,
    const float* __restrict__ rowl, float* __restrict__ outres)
{
    __shared__ unsigned short Pl[2][64 * 32];     //  8 KB
    __shared__ unsigned short Vl[2][256 * 32];    // 32 KB
    const int blk = blockIdx.x;
    const int xcd = blk & 7;
    const int b   = xcd >> 1;
    const int ch  = xcd & 1;
    const int q0  = (blk >> 3) * 64;
    const int t    = threadIdx.x;
    const int wave = t >> 6, lane = t & 63, quad = lane >> 4, l16 = lane & 15;
    const int qw = wave >> 2;            // 0..1 -> 32-q strip
    const int cw = wave & 3;             // 0..3 -> 64-c strip
    const int cbase = cw * 64;

    const unsigned short* Pg = P + ((size_t)b * 128 * NPIX + q0) * 32;
    const unsigned short* Vg = V + ((size_t)b * 128 * CH + ch * 256) * 32;

    // per-thread swizzled LDS byte offsets (constant over the K loop)
    const int fx  = (l16 & 7) << 4;
    const int pA0 = (((qw * 32      + l16) * 64) + quad * 16) ^ fx;
    const int pA1 = (((qw * 32 + 16 + l16) * 64) + quad * 16) ^ fx;
    const int vO0 = (((cbase +  0 + l16) * 64) + quad * 16) ^ fx;
    const int vO1 = (((cbase + 16 + l16) * 64) + quad * 16) ^ fx;
    const int vO2 = (((cbase + 32 + l16) * 64) + quad * 16) ^ fx;
    const int vO3 = (((cbase + 48 + l16) * 64) + quad * 16) ^ fx;

    f32x4 O[2][4];
    #pragma unroll
    for (int qs = 0; qs < 2; ++qs)
        #pragma unroll
        for (int ct = 0; ct < 4; ++ct) O[qs][ct] = (f32x4){0.f, 0.f, 0.f, 0.f};

    // stage K-tile kb into buffer bb: each wave 2x1KB of V; waves 0-3 1KB of P
    auto stage = [&](int bb, int kb) {
        const unsigned short* vg = Vg + (size_t)kb * (CH * 32) + wave * 1024;
        unsigned short* vl = &Vl[bb][wave * 1024];
        gload16(vg + lane * 8,       vl);
        gload16(vg + 512 + lane * 8, vl + 512);
        if (wave < 4) {
            const unsigned short* pg = Pg + (size_t)kb * (NPIX * 32) + wave * 512;
            gload16(pg + lane * 8, &Pl[bb][wave * 512]);
        }
    };

    stage(0, 0);
    __syncthreads();

    int buf = 0;
    for (int kb = 0; kb < 128; ++kb) {
        if (kb + 1 < 128) stage(buf ^ 1, kb + 1);   // in flight across compute

        const char* pb = (const char*)&Pl[buf][0];
        const char* vb = (const char*)&Vl[buf][0];
        bf16x8 a0 = *(const bf16x8*)(pb + pA0);
        bf16x8 a1 = *(const bf16x8*)(pb + pA1);
        bf16x8 v0 = *(const bf16x8*)(vb + vO0);
        bf16x8 v1 = *(const bf16x8*)(vb + vO1);
        bf16x8 v2 = *(const bf16x8*)(vb + vO2);
        bf16x8 v3 = *(const bf16x8*)(vb + vO3);
        O[0][0] = MFMA16(a0, v0, O[0][0]);
        O[1][0] = MFMA16(a1, v0, O[1][0]);
        O[0][1] = MFMA16(a0, v1, O[0][1]);
        O[1][1] = MFMA16(a1, v1, O[1][1]);
        O[0][2] = MFMA16(a0, v2, O[0][2]);
        O[1][2] = MFMA16(a1, v2, O[1][2]);
        O[0][3] = MFMA16(a0, v3, O[0][3]);
        O[1][3] = MFMA16(a1, v3, O[1][3]);

        __syncthreads();   // drains staged loads + all ds_reads of buf
        buf ^= 1;
    }

    float lr[2][4];
    #pragma unroll
    for (int qs = 0; qs < 2; ++qs)
        #pragma unroll
        for (int r = 0; r < 4; ++r)
            lr[qs][r] = 1.0f / rowl[(size_t)b * NPIX + q0 + qw * 32 + qs * 16 + quad * 4 + r];

    const int cb2 = ch * 256 + cbase;
    #pragma unroll
    for (int qs = 0; qs < 2; ++qs) {
        #pragma unroll
        for (int ct = 0; ct < 4; ++ct) {
            f32x4 o = O[qs][ct];
            o[0] *= lr[qs][0]; o[1] *= lr[qs][1]; o[2] *= lr[qs][2]; o[3] *= lr[qs][3];
            const int c = cb2 + ct * 16 + l16;
            *(f32x4*)&outres[((size_t)b * CH + c) * NPIX + q0 + qw * 32 + qs * 16 + quad * 4] = o;
        }
    }
}

// ---------------------------------------------------------------------------
// colsum: attnacc[b][k] = sum_q P[b][q][k] * linv[q]; reads swizzled P
// (per-thread constant XOR since q stride 16 preserves q&7).
// ---------------------------------------------------------------------------
__global__ __launch_bounds__(256) void colsum_kernel(
    const unsigned short* __restrict__ P, const float* __restrict__ rowl,
    float* __restrict__ attnacc)
{
    __shared__ float CS[16][32];
    const int blk = blockIdx.x;            // b*128 + kb
    const int b  = blk >> 7;
    const int kb = blk & 127;
    const int t  = threadIdx.x;
    const int ko2 = t & 15;
    const int qr  = t >> 4;
    const unsigned short* Pb = P + (size_t)(b * 128 + kb) * (NPIX * 32);
    const float* rl = rowl + (size_t)b * NPIX;
    const int qx = (qr & 7) << 3;          // ushort-unit XOR, thread-constant

    float a0 = 0.f, a1 = 0.f;
    for (int q = qr; q < NPIX; q += 16) {
        unsigned int u = *(const unsigned int*)(Pb + ((q * 32 + ko2 * 2) ^ qx));
        float li = 1.0f / rl[q];
        a0 += __uint_as_float(u << 16) * li;
        a1 += __uint_as_float(u & 0xFFFF0000u) * li;
    }
    CS[qr][ko2 * 2]     = a0;
    CS[qr][ko2 * 2 + 1] = a1;
    __syncthreads();
    if (t < 32) {
        float s = 0.f;
        #pragma unroll
        for (int i = 0; i < 16; ++i) s += CS[i][t];
        attnacc[(size_t)b * NPIX + kb * 32 + t] = s;
    }
}

// ---------------------------------------------------------------------------
// FALLBACK path (used only if ws_size too small for P): round-2 stats+apply.
// apply patched to read the swizzled V image.
// ---------------------------------------------------------------------------
__global__ __launch_bounds__(512, 4) void stats_kernel(
    const unsigned short* __restrict__ F, const unsigned short* __restrict__ G,
    float* __restrict__ rowl)
{
    const int blk = blockIdx.x;
    const int xcd = blk & 7;
    const int b   = xcd >> 1;
    const int kh  = xcd & 1;
    const int q0  = (blk >> 3) * 64;
    const int t    = threadIdx.x;
    const int wave = t >> 6, lane = t & 63, quad = lane >> 4, l16 = lane & 15;
    const int qh = wave >> 2, kw = wave & 3;

    bf16x8 af[2][8];
    #pragma unroll
    for (int qs = 0; qs < 2; ++qs)
        #pragma unroll
        for (int st = 0; st < 8; ++st)
            af[qs][st] = *(const bf16x8*)&F[((size_t)b * NPIX + q0 + qh * 32 + qs * 16 + l16) * HCH + st * 32 + quad * 8];

    float ls[2][4];
    #pragma unroll
    for (int qs = 0; qs < 2; ++qs)
        #pragma unroll
        for (int r = 0; r < 4; ++r) ls[qs][r] = 0.f;

    const unsigned short* Gb = G + (size_t)b * 8 * (NPIX * 32);
    const int kbeg = kh * 2048, kend = kbeg + 2048;
    for (int k0 = kbeg; k0 < kend; k0 += 128) {
        const int kk = k0 + kw * 32;
        f32x4 s[2][2];
        #pragma unroll
        for (int qs = 0; qs < 2; ++qs)
            #pragma unroll
            for (int ks = 0; ks < 2; ++ks) s[qs][ks] = (f32x4){0.f, 0.f, 0.f, 0.f};
        #pragma unroll
        for (int st = 0; st < 8; ++st) {
            const unsigned short* gs = Gb + (size_t)st * (NPIX * 32) + quad * 8;
            bf16x8 b0 = *(const bf16x8*)(gs + (size_t)(kk + l16) * 32);
            bf16x8 b1 = *(const bf16x8*)(gs + (size_t)(kk + 16 + l16) * 32);
            s[0][0] = MFMA16(af[0][st], b0, s[0][0]);
            s[1][0] = MFMA16(af[1][st], b0, s[1][0]);
            s[0][1] = MFMA16(af[0][st], b1, s[0][1]);
            s[1][1] = MFMA16(af[1][st], b1, s[1][1]);
        }
        #pragma unroll
        for (int qs = 0; qs < 2; ++qs)
            #pragma unroll
            for (int r = 0; r < 4; ++r)
                ls[qs][r] += exp2f(L2E * s[qs][0][r]) + exp2f(L2E * s[qs][1][r]);
    }

    #pragma unroll
    for (int d = 1; d < 16; d <<= 1)
        #pragma unroll
        for (int qs = 0; qs < 2; ++qs)
            #pragma unroll
            for (int r = 0; r < 4; ++r) ls[qs][r] += __shfl_xor(ls[qs][r], d, 64);

    if (l16 == 0) {
        #pragma unroll
        for (int qs = 0; qs < 2; ++qs)
            #pragma unroll
            for (int r = 0; r < 4; ++r)
                atomicAdd(&rowl[(size_t)b * NPIX + q0 + qh * 32 + qs * 16 + quad * 4 + r], ls[qs][r]);
    }
}

__global__ __launch_bounds__(512, 4) void apply_kernel(
    const unsigned short* __restrict__ F, const unsigned short* __restrict__ G,
    const unsigned short* __restrict__ V, const float* __restrict__ rowl,
    float* __restrict__ outres, float* __restrict__ attnacc)
{
    __shared__ unsigned short Pl[2][32][136];
    const int blk = blockIdx.x;
    const int xcd = blk & 7;
    const int b   = xcd >> 1;
    const int ch  = xcd & 1;
    const int q0  = (blk >> 3) * 32;
    const int t    = threadIdx.x;
    const int wave = t >> 6, lane = t & 63, quad = lane >> 4, l16 = lane & 15;
    const int cw = ch * 256 + wave * 32;
    const int vx = (l16 & 7) << 3;   // V image XOR (ushort units)

    float linv[2][4];
    #pragma unroll
    for (int qs = 0; qs < 2; ++qs)
        #pragma unroll
        for (int r = 0; r < 4; ++r)
            linv[qs][r] = 1.0f / rowl[(size_t)b * NPIX + q0 + qs * 16 + quad * 4 + r];

    f32x4 O[2][2];
    #pragma unroll
    for (int qs = 0; qs < 2; ++qs)
        #pragma unroll
        for (int ct = 0; ct < 2; ++ct) O[qs][ct] = (f32x4){0.f, 0.f, 0.f, 0.f};

    const unsigned short* Gb = G + (size_t)b * 8 * (NPIX * 32);
    const unsigned short* Vb = V + (size_t)b * 128 * (CH * 32);
    const unsigned short* Fq = F + ((size_t)b * NPIX + q0) * HCH;

    int buf = 0;
    for (int k0 = 0; k0 < NPIX; k0 += 128) {
        const int kk = k0 + wave * 16;
        f32x4 s[2];
        s[0] = (f32x4){0.f, 0.f, 0.f, 0.f};
        s[1] = (f32x4){0.f, 0.f, 0.f, 0.f};
        #pragma unroll
        for (int st = 0; st < 8; ++st) {
            bf16x8 a0 = *(const bf16x8*)&Fq[(size_t)l16 * HCH + st * 32 + quad * 8];
            bf16x8 a1 = *(const bf16x8*)&Fq[(size_t)(16 + l16) * HCH + st * 32 + quad * 8];
            bf16x8 bg = *(const bf16x8*)(Gb + (size_t)st * (NPIX * 32) + (size_t)(kk + l16) * 32 + quad * 8);
            s[0] = MFMA16(a0, bg, s[0]);
            s[1] = MFMA16(a1, bg, s[1]);
        }

        float p[2][4];
        #pragma unroll
        for (int qs = 0; qs < 2; ++qs)
            #pragma unroll
            for (int r = 0; r < 4; ++r)
                p[qs][r] = exp2f(L2E * s[qs][r]) * linv[qs][r];

        #pragma unroll
        for (int qs = 0; qs < 2; ++qs)
            #pragma unroll
            for (int r = 0; r < 4; ++r)
                Pl[buf][qs * 16 + quad * 4 + r][wave * 16 + l16] = f2bf(p[qs][r]);

        if (ch == 0) {
            float cs = p[0][0] + p[0][1] + p[0][2] + p[0][3]
                     + p[1][0] + p[1][1] + p[1][2] + p[1][3];
            cs += __shfl_xor(cs, 16, 64);
            cs += __shfl_xor(cs, 32, 64);
            if (quad == 0)
                atomicAdd(&attnacc[(size_t)b * NPIX + kk + l16], cs);
        }

        __syncthreads();

        #pragma unroll
        for (int ks = 0; ks < 4; ++ks) {
            bf16x8 pa0 = *(const bf16x8*)&Pl[buf][l16][ks * 32 + quad * 8];
            bf16x8 pa1 = *(const bf16x8*)&Pl[buf][16 + l16][ks * 32 + quad * 8];
            const unsigned short* vs = Vb + ((size_t)(k0 >> 5) + ks) * (CH * 32);
            #pragma unroll
            for (int ct = 0; ct < 2; ++ct) {
                const int el = (((cw + ct * 16 + l16) * 32) + quad * 8) ^ vx;
                bf16x8 vv = *(const bf16x8*)(vs + el);
                O[0][ct] = MFMA16(pa0, vv, O[0][ct]);
                O[1][ct] = MFMA16(pa1, vv, O[1][ct]);
            }
        }
        buf ^= 1;
    }

    #pragma unroll
    for (int qs = 0; qs < 2; ++qs) {
        #pragma unroll
        for (int ct = 0; ct < 2; ++ct) {
            const int c = cw + ct * 16 + l16;
            *(f32x4*)&outres[((size_t)b * CH + c) * NPIX + q0 + qs * 16 + quad * 4] = O[qs][ct];
        }
    }
}

__global__ __launch_bounds__(256) void attn_fin_kernel(
    const float* __restrict__ acc, float* __restrict__ outa)
{
    const int i = blockIdx.x * 256 + threadIdx.x;
    if (i < BATCH * NPIX) outa[i] = acc[i] * (1.0f / (float)NPIX);
}

extern "C" void kernel_launch(void* const* d_in, const int* in_sizes, int n_in,
                              void* d_out, int out_size, void* d_ws, size_t ws_size,
                              hipStream_t stream)
{
    (void)in_sizes; (void)n_in; (void)out_size;
    const float* x  = (const float*)d_in[0];
    const float* Wf = (const float*)d_in[1];
    const float* bf = (const float*)d_in[2];
    const float* Wg = (const float*)d_in[3];
    const float* bg = (const float*)d_in[4];
    const float* Wh = (const float*)d_in[5];
    const float* bh = (const float*)d_in[6];
    float* out = (float*)d_out;

    const size_t P_ELEMS  = (size_t)BATCH * 128 * NPIX * 32;   // 67,108,864
    const size_t XP_ELEMS = (size_t)BATCH * 16 * NPIX * 32;    //  8,388,608
    const size_t F_ELEMS  = (size_t)BATCH * NPIX * HCH;        //  4,194,304
    const size_t V_ELEMS  = (size_t)BATCH * 128 * CH * 32;     //  8,388,608
    const size_t NEED = (P_ELEMS + 2 * F_ELEMS + V_ELEMS) * 2
                      + (size_t)2 * BATCH * NPIX * 4;          // ~167.9 MB

    if (ws_size >= NEED) {
        // ---- materialized-P path. P overlays Xp+Wc (dead before score).
        unsigned short* P  = (unsigned short*)d_ws;
        unsigned short* Xp = P;
        unsigned short* Wc = P + XP_ELEMS;
        unsigned short* F  = P + P_ELEMS;
        unsigned short* G  = F + F_ELEMS;
        unsigned short* V  = G + F_ELEMS;
        float* rowl    = (float*)(V + V_ELEMS);
        float* attnacc = rowl + (size_t)BATCH * NPIX;

        hipMemsetAsync(rowl, 0, (size_t)BATCH * NPIX * sizeof(float), stream);

        convert_w_kernel<<<512, 256, 0, stream>>>(Wf, Wg, Wh, Wc);
        convert_x_kernel<<<dim3(NPIX / 64, 16, BATCH), 256, 0, stream>>>(x, Xp);

        proj_fg_kernel<<<dim3(NPIX / 128, 4, BATCH), 256, 0, stream>>>(Wc, Xp, bf, bg, F, G);
        proj_v_kernel<<<dim3(4, NPIX / 128, BATCH), 256, 0, stream>>>(Wc, Xp, bh, V);

        score_kernel<<<512, 512, 0, stream>>>(F, G, P, rowl);
        pv_kernel<<<512, 512, 0, stream>>>(P, V, rowl, out);
        colsum_kernel<<<512, 256, 0, stream>>>(P, rowl, attnacc);

        attn_fin_kernel<<<BATCH * NPIX / 256, 256, 0, stream>>>(
            attnacc, out + (size_t)BATCH * CH * NPIX);
    } else {
        // ---- fallback: round-2 layout & kernels (V image swizzled; apply
        // reads it with the same XOR).
        unsigned short* Xp = (unsigned short*)d_ws;
        unsigned short* Wc = Xp + XP_ELEMS;
        unsigned short* F  = Wc + (size_t)1024 * CH;
        unsigned short* G  = F + F_ELEMS;
        unsigned short* V  = G + F_ELEMS;
        float* rowl    = (float*)(V + V_ELEMS);
        float* attnacc = rowl + (size_t)BATCH * NPIX;

        hipMemsetAsync(rowl, 0, (size_t)2 * BATCH * NPIX * sizeof(float), stream);

        convert_w_kernel<<<512, 256, 0, stream>>>(Wf, Wg, Wh, Wc);
        convert_x_kernel<<<dim3(NPIX / 64, 16, BATCH), 256, 0, stream>>>(x, Xp);

        proj_fg_kernel<<<dim3(NPIX / 128, 4, BATCH), 256, 0, stream>>>(Wc, Xp, bf, bg, F, G);
        proj_v_kernel<<<dim3(4, NPIX / 128, BATCH), 256, 0, stream>>>(Wc, Xp, bh, V);

        stats_kernel<<<512, 512, 0, stream>>>(F, G, rowl);
        apply_kernel<<<1024, 512, 0, stream>>>(F, G, V, rowl, out, attnacc);

        attn_fin_kernel<<<BATCH * NPIX / 256, 256, 0, stream>>>(
            attnacc, out + (size_t)BATCH * CH * NPIX);
    }
}

// Round 7
// 414.977 us; speedup vs baseline: 1.7709x; 1.1161x over previous
//
#include <hip/hip_runtime.h>
#include <cmath>

#define BATCH 4
#define CH    512
#define HCH   256
#define NPIX  4096
#define L2E   1.44269504088896340736f

typedef __attribute__((ext_vector_type(8))) short bf16x8;
typedef __attribute__((ext_vector_type(4))) float f32x4;

#define MFMA16(a, b, c) __builtin_amdgcn_mfma_f32_16x16x32_bf16((a), (b), (c), 0, 0, 0)

__device__ __forceinline__ unsigned short f2bf(float f) {
    unsigned int u = __float_as_uint(f);
    return (unsigned short)((u + 0x7fffu + ((u >> 16) & 1u)) >> 16);
}
__device__ __forceinline__ ushort4 pack4(float a, float b, float c, float d) {
    ushort4 u; u.x = f2bf(a); u.y = f2bf(b); u.z = f2bf(c); u.w = f2bf(d); return u;
}
// async global->LDS, 16B per lane; LDS dest is wave-uniform base + lane*16.
__device__ __forceinline__ void gload16(const unsigned short* g, unsigned short* l) {
    __builtin_amdgcn_global_load_lds(
        (const __attribute__((address_space(1))) unsigned int*)g,
        (__attribute__((address_space(3))) unsigned int*)l, 16, 0, 0);
}

// ---------------------------------------------------------------------------
// Wc[1024][512] bf16 = concat(Wf, Wg, Wh) rows, K-contiguous.
// ---------------------------------------------------------------------------
__global__ __launch_bounds__(256) void convert_w_kernel(
    const float* __restrict__ Wf, const float* __restrict__ Wg,
    const float* __restrict__ Wh, unsigned short* __restrict__ Wc)
{
    const int idx = blockIdx.x * 256 + threadIdx.x;
    const int o  = idx >> 7;
    const int c4 = (idx & 127) * 4;
    const float* src = (o < HCH)     ? (Wf + (size_t)o * CH + c4)
                     : (o < 2 * HCH) ? (Wg + (size_t)(o - HCH) * CH + c4)
                                     : (Wh + (size_t)(o - 2 * HCH) * CH + c4);
    float4 v = *(const float4*)src;
    *(ushort4*)&Wc[(size_t)o * CH + c4] = pack4(v.x, v.y, v.z, v.w);
}

// ---------------------------------------------------------------------------
// X' swizzle: x fp32 [b][512][4096] -> bf16 [b][cb=16][n=4096][co=32].
// ---------------------------------------------------------------------------
__global__ __launch_bounds__(256) void convert_x_kernel(
    const float* __restrict__ x, unsigned short* __restrict__ Xp)
{
    __shared__ unsigned short Lt[64][40];
    const int b  = blockIdx.z;
    const int cb = blockIdx.y;
    const int n0 = blockIdx.x * 64;
    const int t  = threadIdx.x;
    const int cr = t >> 4;
    const int f4 = t & 15;
    #pragma unroll
    for (int p = 0; p < 2; ++p) {
        const int c = p * 16 + cr;
        float4 v = *(const float4*)(x + ((size_t)b * CH + cb * 32 + c) * NPIX + n0 + f4 * 4);
        Lt[f4 * 4 + 0][c] = f2bf(v.x);
        Lt[f4 * 4 + 1][c] = f2bf(v.y);
        Lt[f4 * 4 + 2][c] = f2bf(v.z);
        Lt[f4 * 4 + 3][c] = f2bf(v.w);
    }
    __syncthreads();
    const int n  = t >> 2;
    const int ch = t & 3;
    uint4 u = *(const uint4*)&Lt[n][ch * 8];
    *(uint4*)&Xp[((size_t)b * 16 + cb) * (NPIX * 32) + (size_t)(n0 + n) * 32 + ch * 8] = u;
}

// ---------------------------------------------------------------------------
// proj F/G: n-tile halved 128->64 (grid.x 32->64) -> 4 blk/CU, 16 waves/CU
// (was 8; latency-bound at 25% occupancy). acc[2][4] = 32 AGPR.
// G written in the XOR-swizzled image (el ^= ((n&7)<<3), ushort units) so
// score can global_load_lds it linearly and ds_read conflict-free.
// ---------------------------------------------------------------------------
__global__ __launch_bounds__(256, 4) void proj_fg_kernel(
    const unsigned short* __restrict__ Wc, const unsigned short* __restrict__ Xp,
    const float* __restrict__ bf, const float* __restrict__ bg,
    unsigned short* __restrict__ F, unsigned short* __restrict__ G)
{
    const int b  = blockIdx.z;
    const int n0 = blockIdx.x * 64;
    const int o0 = blockIdx.y * 128;
    const int t  = threadIdx.x;
    const int wave = t >> 6, lane = t & 63, quad = lane >> 4, l16 = lane & 15;
    const int ow = o0 + wave * 32;

    f32x4 acc[2][4];
    #pragma unroll
    for (int ms = 0; ms < 2; ++ms)
        #pragma unroll
        for (int ns = 0; ns < 4; ++ns) acc[ms][ns] = (f32x4){0.f, 0.f, 0.f, 0.f};

    const unsigned short* xb = Xp + (size_t)b * 16 * (NPIX * 32);
    for (int st = 0; st < 16; ++st) {
        bf16x8 a0 = *(const bf16x8*)&Wc[(size_t)(ow + l16) * CH + st * 32 + quad * 8];
        bf16x8 a1 = *(const bf16x8*)&Wc[(size_t)(ow + 16 + l16) * CH + st * 32 + quad * 8];
        const unsigned short* xs = xb + (size_t)st * (NPIX * 32) + quad * 8;
        #pragma unroll
        for (int ns = 0; ns < 4; ++ns) {
            bf16x8 bb = *(const bf16x8*)(xs + (size_t)(n0 + ns * 16 + l16) * 32);
            acc[0][ns] = MFMA16(a0, bb, acc[0][ns]);
            acc[1][ns] = MFMA16(a1, bb, acc[1][ns]);
        }
    }

    const int orow = quad * 4;
    const int gx = (l16 & 7) << 3;   // n&7 == l16&7, ushort units
    #pragma unroll
    for (int ms = 0; ms < 2; ++ms) {
        const int ob = ow + ms * 16 + orow;
        float bias[4];
        #pragma unroll
        for (int r = 0; r < 4; ++r)
            bias[r] = (o0 < HCH) ? bf[ob + r] : bg[ob + r - HCH];
        #pragma unroll
        for (int ns = 0; ns < 4; ++ns) {
            const int n = n0 + ns * 16 + l16;
            ushort4 u = pack4(acc[ms][ns][0] + bias[0], acc[ms][ns][1] + bias[1],
                              acc[ms][ns][2] + bias[2], acc[ms][ns][3] + bias[3]);
            if (o0 < HCH) {
                *(ushort4*)&F[((size_t)b * NPIX + n) * HCH + ob] = u;
            } else {
                const int og = ob - HCH;
                const int cb = og >> 5, co = og & 31;
                const int el = (n * 32 + co) ^ gx;   // swizzled image
                *(ushort4*)&G[((size_t)b * 8 + cb) * (NPIX * 32) + el] = u;
            }
        }
    }
}

// ---------------------------------------------------------------------------
// proj V: c-tile halved 128->64 (grid.x 4->8) -> 4 blk/CU. Output layout
// [b][kb=128][c=512][ko=32] in XOR-swizzled image (el ^= ((c&7)<<3)).
// ---------------------------------------------------------------------------
__global__ __launch_bounds__(256, 4) void proj_v_kernel(
    const unsigned short* __restrict__ Wc, const unsigned short* __restrict__ Xp,
    const float* __restrict__ bh, unsigned short* __restrict__ V)
{
    const int b  = blockIdx.z;
    const int c0 = blockIdx.x * 64;
    const int p0 = blockIdx.y * 128;
    const int t  = threadIdx.x;
    const int wave = t >> 6, lane = t & 63, quad = lane >> 4, l16 = lane & 15;
    const int pw = p0 + wave * 32;

    f32x4 acc[2][4];
    #pragma unroll
    for (int ms = 0; ms < 2; ++ms)
        #pragma unroll
        for (int ns = 0; ns < 4; ++ns) acc[ms][ns] = (f32x4){0.f, 0.f, 0.f, 0.f};

    const unsigned short* xb = Xp + (size_t)b * 16 * (NPIX * 32);
    for (int st = 0; st < 16; ++st) {
        const unsigned short* xs = xb + (size_t)st * (NPIX * 32) + quad * 8;
        bf16x8 a0 = *(const bf16x8*)(xs + (size_t)(pw + l16) * 32);
        bf16x8 a1 = *(const bf16x8*)(xs + (size_t)(pw + 16 + l16) * 32);
        #pragma unroll
        for (int ns = 0; ns < 4; ++ns) {
            bf16x8 bb = *(const bf16x8*)&Wc[(size_t)(2 * HCH + c0 + ns * 16 + l16) * CH + st * 32 + quad * 8];
            acc[0][ns] = MFMA16(a0, bb, acc[0][ns]);
            acc[1][ns] = MFMA16(a1, bb, acc[1][ns]);
        }
    }

    float biasv[4];
    #pragma unroll
    for (int ns = 0; ns < 4; ++ns) biasv[ns] = bh[c0 + ns * 16 + l16];

    const int kb = pw >> 5;
    const int ko0 = quad * 4;
    const int cx = (l16 & 7) << 3;   // c&7 == l16&7, ushort units
    #pragma unroll
    for (int ms = 0; ms < 2; ++ms) {
        #pragma unroll
        for (int ns = 0; ns < 4; ++ns) {
            const int c = c0 + ns * 16 + l16;
            ushort4 u = pack4(acc[ms][ns][0] + biasv[ns], acc[ms][ns][1] + biasv[ns],
                              acc[ms][ns][2] + biasv[ns], acc[ms][ns][3] + biasv[ns]);
            const int el = (c * 32 + ms * 16 + ko0) ^ cx;   // swizzled image
            *(ushort4*)&V[((size_t)b * 128 + kb) * (CH * 32) + el] = u;
        }
    }
}

// ---------------------------------------------------------------------------
// score v2: m97-style LDS-staged QK^T. Block = 64q x 2048k (kh half), 512
// thr (8 waves = 2qh x 4kw). k-tile = 64 keys: G tile 8cb x 64k x 32co =
// 32 KB staged via global_load_lds (double-buffered 64 KB -> 2 blk/CU),
// ONE barrier per tile. G image pre-swizzled so the linear LDS copy gives
// conflict-free ds_read_b128 (byte ^= ((key&7)<<4)). af stays resident
// (A operand, AGPR side). P = exp2(S) stored swizzled as before.
// Round-6 diagnosis: old score had VGPR=64, zero G-prefetch depth ->
// per-tile L2 latency exposure (MfmaUtil 12%). Same fix as pv.
// ---------------------------------------------------------------------------
__global__ __launch_bounds__(512, 4) void score_kernel(
    const unsigned short* __restrict__ F, const unsigned short* __restrict__ G,
    unsigned short* __restrict__ P, float* __restrict__ rowl)
{
    __shared__ unsigned short Gl[2][8 * 64 * 32];   // 2 x 32 KB
    const int blk = blockIdx.x;
    const int xcd = blk & 7;
    const int b   = xcd >> 1;
    const int kh  = xcd & 1;
    const int q0  = (blk >> 3) * 64;
    const int t    = threadIdx.x;
    const int wave = t >> 6, lane = t & 63, quad = lane >> 4, l16 = lane & 15;
    const int qh = wave >> 2, kw = wave & 3;

    bf16x8 af[2][8];
    #pragma unroll
    for (int qs = 0; qs < 2; ++qs)
        #pragma unroll
        for (int st = 0; st < 8; ++st)
            af[qs][st] = *(const bf16x8*)&F[((size_t)b * NPIX + q0 + qh * 32 + qs * 16 + l16) * HCH + st * 32 + quad * 8];

    float ls[2][4];
    #pragma unroll
    for (int qs = 0; qs < 2; ++qs)
        #pragma unroll
        for (int r = 0; r < 4; ++r) ls[qs][r] = 0.f;

    const unsigned short* Gb = G + (size_t)b * 8 * (NPIX * 32);
    unsigned short* Pb2 = P + (size_t)b * 128 * (NPIX * 32) + (size_t)(q0 + qh * 32) * 32;
    const int qx = (quad & 1) * 4;   // (q&7) = qx + r for row q = ...+quad*4+r

    const int kbeg = kh * 2048;

    // stage keys [kbeg + kt*64, +64) of all 8 cb panels into Gl[bb].
    // 2048 x 16B chunks; wave w, pass j covers chunks [j*512 + w*64, +64)
    // (aligned within one 256-chunk panel). Linear copy of swizzled image.
    auto stage = [&](int bb, int kt) {
        const size_t kofs = (size_t)(kbeg + kt * 64) * 32;
        #pragma unroll
        for (int j = 0; j < 4; ++j) {
            const int cbse = j * 512 + wave * 64;     // wave-uniform chunk base
            const int cb   = cbse >> 8;
            const int o16  = cbse & 255;
            const unsigned short* g = Gb + (size_t)cb * (NPIX * 32) + kofs
                                        + o16 * 8 + lane * 8;
            gload16(g, &Gl[bb][cb * 2048 + o16 * 8]);
        }
    };

    // per-thread swizzled ds_read byte offsets (constant over k loop)
    const int fx = (l16 & 7) << 4;
    const int bO = (((kw * 16 + l16) * 64) + quad * 16) ^ fx;

    stage(0, 0);
    __syncthreads();

    int buf = 0;
    for (int kt = 0; kt < 32; ++kt) {
        if (kt + 1 < 32) stage(buf ^ 1, kt + 1);   // in flight across compute

        f32x4 s[2];
        s[0] = (f32x4){0.f, 0.f, 0.f, 0.f};
        s[1] = (f32x4){0.f, 0.f, 0.f, 0.f};
        const char* gb = (const char*)&Gl[buf][0];
        #pragma unroll
        for (int st = 0; st < 8; ++st) {
            bf16x8 bb = *(const bf16x8*)(gb + st * 4096 + bO);
            s[0] = MFMA16(af[0][st], bb, s[0]);
            s[1] = MFMA16(af[1][st], bb, s[1]);
        }

        // P store: keys kkk = kbeg + kt*64 + kw*16; kb = kkk>>5, col = (kw&1)*16+l16
        const int kkk = kbeg + kt * 64 + kw * 16;
        unsigned short* pw = Pb2 + (size_t)(kkk >> 5) * (NPIX * 32);
        const int kcol = (kw & 1) * 16 + l16;
        #pragma unroll
        for (int qs = 0; qs < 2; ++qs)
            #pragma unroll
            for (int r = 0; r < 4; ++r) {
                float e = exp2f(L2E * s[qs][r]);
                const int el = ((qs * 16 + quad * 4 + r) * 32 + kcol) ^ ((qx + r) << 3);
                pw[el] = f2bf(e);
                ls[qs][r] += e;
            }

        __syncthreads();
        buf ^= 1;
    }

    #pragma unroll
    for (int d = 1; d < 16; d <<= 1)
        #pragma unroll
        for (int qs = 0; qs < 2; ++qs)
            #pragma unroll
            for (int r = 0; r < 4; ++r) ls[qs][r] += __shfl_xor(ls[qs][r], d, 64);

    if (l16 == 0) {
        #pragma unroll
        for (int qs = 0; qs < 2; ++qs)
            #pragma unroll
            for (int r = 0; r < 4; ++r)
                atomicAdd(&rowl[(size_t)b * NPIX + q0 + qh * 32 + qs * 16 + quad * 4 + r], ls[qs][r]);
    }
}

// ---------------------------------------------------------------------------
// pv v3 (unchanged, round-6 verified): LDS-double-buffered GEMM.
// ---------------------------------------------------------------------------
__global__ __launch_bounds__(512, 4) void pv_kernel(
    const unsigned short* __restrict__ P, const unsigned short* __restrict__ V,
    const float* __restrict__ rowl, float* __restrict__ outres)
{
    __shared__ unsigned short Pl[2][64 * 32];     //  8 KB
    __shared__ unsigned short Vl[2][256 * 32];    // 32 KB
    const int blk = blockIdx.x;
    const int xcd = blk & 7;
    const int b   = xcd >> 1;
    const int ch  = xcd & 1;
    const int q0  = (blk >> 3) * 64;
    const int t    = threadIdx.x;
    const int wave = t >> 6, lane = t & 63, quad = lane >> 4, l16 = lane & 15;
    const int qw = wave >> 2;            // 0..1 -> 32-q strip
    const int cw = wave & 3;             // 0..3 -> 64-c strip
    const int cbase = cw * 64;

    const unsigned short* Pg = P + ((size_t)b * 128 * NPIX + q0) * 32;
    const unsigned short* Vg = V + ((size_t)b * 128 * CH + ch * 256) * 32;

    const int fx  = (l16 & 7) << 4;
    const int pA0 = (((qw * 32      + l16) * 64) + quad * 16) ^ fx;
    const int pA1 = (((qw * 32 + 16 + l16) * 64) + quad * 16) ^ fx;
    const int vO0 = (((cbase +  0 + l16) * 64) + quad * 16) ^ fx;
    const int vO1 = (((cbase + 16 + l16) * 64) + quad * 16) ^ fx;
    const int vO2 = (((cbase + 32 + l16) * 64) + quad * 16) ^ fx;
    const int vO3 = (((cbase + 48 + l16) * 64) + quad * 16) ^ fx;

    f32x4 O[2][4];
    #pragma unroll
    for (int qs = 0; qs < 2; ++qs)
        #pragma unroll
        for (int ct = 0; ct < 4; ++ct) O[qs][ct] = (f32x4){0.f, 0.f, 0.f, 0.f};

    auto stage = [&](int bb, int kb) {
        const unsigned short* vg = Vg + (size_t)kb * (CH * 32) + wave * 1024;
        unsigned short* vl = &Vl[bb][wave * 1024];
        gload16(vg + lane * 8,       vl);
        gload16(vg + 512 + lane * 8, vl + 512);
        if (wave < 4) {
            const unsigned short* pg = Pg + (size_t)kb * (NPIX * 32) + wave * 512;
            gload16(pg + lane * 8, &Pl[bb][wave * 512]);
        }
    };

    stage(0, 0);
    __syncthreads();

    int buf = 0;
    for (int kb = 0; kb < 128; ++kb) {
        if (kb + 1 < 128) stage(buf ^ 1, kb + 1);

        const char* pb = (const char*)&Pl[buf][0];
        const char* vb = (const char*)&Vl[buf][0];
        bf16x8 a0 = *(const bf16x8*)(pb + pA0);
        bf16x8 a1 = *(const bf16x8*)(pb + pA1);
        bf16x8 v0 = *(const bf16x8*)(vb + vO0);
        bf16x8 v1 = *(const bf16x8*)(vb + vO1);
        bf16x8 v2 = *(const bf16x8*)(vb + vO2);
        bf16x8 v3 = *(const bf16x8*)(vb + vO3);
        O[0][0] = MFMA16(a0, v0, O[0][0]);
        O[1][0] = MFMA16(a1, v0, O[1][0]);
        O[0][1] = MFMA16(a0, v1, O[0][1]);
        O[1][1] = MFMA16(a1, v1, O[1][1]);
        O[0][2] = MFMA16(a0, v2, O[0][2]);
        O[1][2] = MFMA16(a1, v2, O[1][2]);
        O[0][3] = MFMA16(a0, v3, O[0][3]);
        O[1][3] = MFMA16(a1, v3, O[1][3]);

        __syncthreads();
        buf ^= 1;
    }

    float lr[2][4];
    #pragma unroll
    for (int qs = 0; qs < 2; ++qs)
        #pragma unroll
        for (int r = 0; r < 4; ++r)
            lr[qs][r] = 1.0f / rowl[(size_t)b * NPIX + q0 + qw * 32 + qs * 16 + quad * 4 + r];

    const int cb2 = ch * 256 + cbase;
    #pragma unroll
    for (int qs = 0; qs < 2; ++qs) {
        #pragma unroll
        for (int ct = 0; ct < 4; ++ct) {
            f32x4 o = O[qs][ct];
            o[0] *= lr[qs][0]; o[1] *= lr[qs][1]; o[2] *= lr[qs][2]; o[3] *= lr[qs][3];
            const int c = cb2 + ct * 16 + l16;
            *(f32x4*)&outres[((size_t)b * CH + c) * NPIX + q0 + qw * 32 + qs * 16 + quad * 4] = o;
        }
    }
}

// ---------------------------------------------------------------------------
// colsum (unchanged, round-6 verified).
// ---------------------------------------------------------------------------
__global__ __launch_bounds__(256) void colsum_kernel(
    const unsigned short* __restrict__ P, const float* __restrict__ rowl,
    float* __restrict__ attnacc)
{
    __shared__ float CS[16][32];
    const int blk = blockIdx.x;            // b*128 + kb
    const int b  = blk >> 7;
    const int kb = blk & 127;
    const int t  = threadIdx.x;
    const int ko2 = t & 15;
    const int qr  = t >> 4;
    const unsigned short* Pb = P + (size_t)(b * 128 + kb) * (NPIX * 32);
    const float* rl = rowl + (size_t)b * NPIX;
    const int qx = (qr & 7) << 3;

    float a0 = 0.f, a1 = 0.f;
    for (int q = qr; q < NPIX; q += 16) {
        unsigned int u = *(const unsigned int*)(Pb + ((q * 32 + ko2 * 2) ^ qx));
        float li = 1.0f / rl[q];
        a0 += __uint_as_float(u << 16) * li;
        a1 += __uint_as_float(u & 0xFFFF0000u) * li;
    }
    CS[qr][ko2 * 2]     = a0;
    CS[qr][ko2 * 2 + 1] = a1;
    __syncthreads();
    if (t < 32) {
        float s = 0.f;
        #pragma unroll
        for (int i = 0; i < 16; ++i) s += CS[i][t];
        attnacc[(size_t)b * NPIX + kb * 32 + t] = s;
    }
}

// ---------------------------------------------------------------------------
// FALLBACK path (used only if ws_size too small for P): stats+apply reading
// the swizzled G/V images with matching thread-constant XORs.
// ---------------------------------------------------------------------------
__global__ __launch_bounds__(512, 4) void stats_kernel(
    const unsigned short* __restrict__ F, const unsigned short* __restrict__ G,
    float* __restrict__ rowl)
{
    const int blk = blockIdx.x;
    const int xcd = blk & 7;
    const int b   = xcd >> 1;
    const int kh  = xcd & 1;
    const int q0  = (blk >> 3) * 64;
    const int t    = threadIdx.x;
    const int wave = t >> 6, lane = t & 63, quad = lane >> 4, l16 = lane & 15;
    const int qh = wave >> 2, kw = wave & 3;
    const int gx = (l16 & 7) << 3;   // G image XOR (ushort units)

    bf16x8 af[2][8];
    #pragma unroll
    for (int qs = 0; qs < 2; ++qs)
        #pragma unroll
        for (int st = 0; st < 8; ++st)
            af[qs][st] = *(const bf16x8*)&F[((size_t)b * NPIX + q0 + qh * 32 + qs * 16 + l16) * HCH + st * 32 + quad * 8];

    float ls[2][4];
    #pragma unroll
    for (int qs = 0; qs < 2; ++qs)
        #pragma unroll
        for (int r = 0; r < 4; ++r) ls[qs][r] = 0.f;

    const unsigned short* Gb = G + (size_t)b * 8 * (NPIX * 32);
    const int kbeg = kh * 2048, kend = kbeg + 2048;
    for (int k0 = kbeg; k0 < kend; k0 += 128) {
        const int kk = k0 + kw * 32;
        f32x4 s[2][2];
        #pragma unroll
        for (int qs = 0; qs < 2; ++qs)
            #pragma unroll
            for (int ks = 0; ks < 2; ++ks) s[qs][ks] = (f32x4){0.f, 0.f, 0.f, 0.f};
        #pragma unroll
        for (int st = 0; st < 8; ++st) {
            const unsigned short* gs = Gb + (size_t)st * (NPIX * 32);
            bf16x8 b0 = *(const bf16x8*)(gs + ((((kk + l16) * 32) + quad * 8) ^ gx));
            bf16x8 b1 = *(const bf16x8*)(gs + ((((kk + 16 + l16) * 32) + quad * 8) ^ gx));
            s[0][0] = MFMA16(af[0][st], b0, s[0][0]);
            s[1][0] = MFMA16(af[1][st], b0, s[1][0]);
            s[0][1] = MFMA16(af[0][st], b1, s[0][1]);
            s[1][1] = MFMA16(af[1][st], b1, s[1][1]);
        }
        #pragma unroll
        for (int qs = 0; qs < 2; ++qs)
            #pragma unroll
            for (int r = 0; r < 4; ++r)
                ls[qs][r] += exp2f(L2E * s[qs][0][r]) + exp2f(L2E * s[qs][1][r]);
    }

    #pragma unroll
    for (int d = 1; d < 16; d <<= 1)
        #pragma unroll
        for (int qs = 0; qs < 2; ++qs)
            #pragma unroll
            for (int r = 0; r < 4; ++r) ls[qs][r] += __shfl_xor(ls[qs][r], d, 64);

    if (l16 == 0) {
        #pragma unroll
        for (int qs = 0; qs < 2; ++qs)
            #pragma unroll
            for (int r = 0; r < 4; ++r)
                atomicAdd(&rowl[(size_t)b * NPIX + q0 + qh * 32 + qs * 16 + quad * 4 + r], ls[qs][r]);
    }
}

__global__ __launch_bounds__(512, 4) void apply_kernel(
    const unsigned short* __restrict__ F, const unsigned short* __restrict__ G,
    const unsigned short* __restrict__ V, const float* __restrict__ rowl,
    float* __restrict__ outres, float* __restrict__ attnacc)
{
    __shared__ unsigned short Pl[2][32][136];
    const int blk = blockIdx.x;
    const int xcd = blk & 7;
    const int b   = xcd >> 1;
    const int ch  = xcd & 1;
    const int q0  = (blk >> 3) * 32;
    const int t    = threadIdx.x;
    const int wave = t >> 6, lane = t & 63, quad = lane >> 4, l16 = lane & 15;
    const int cw = ch * 256 + wave * 32;
    const int vx = (l16 & 7) << 3;   // V image XOR (ushort units)
    const int gx = (l16 & 7) << 3;   // G image XOR

    float linv[2][4];
    #pragma unroll
    for (int qs = 0; qs < 2; ++qs)
        #pragma unroll
        for (int r = 0; r < 4; ++r)
            linv[qs][r] = 1.0f / rowl[(size_t)b * NPIX + q0 + qs * 16 + quad * 4 + r];

    f32x4 O[2][2];
    #pragma unroll
    for (int qs = 0; qs < 2; ++qs)
        #pragma unroll
        for (int ct = 0; ct < 2; ++ct) O[qs][ct] = (f32x4){0.f, 0.f, 0.f, 0.f};

    const unsigned short* Gb = G + (size_t)b * 8 * (NPIX * 32);
    const unsigned short* Vb = V + (size_t)b * 128 * (CH * 32);
    const unsigned short* Fq = F + ((size_t)b * NPIX + q0) * HCH;

    int buf = 0;
    for (int k0 = 0; k0 < NPIX; k0 += 128) {
        const int kk = k0 + wave * 16;
        f32x4 s[2];
        s[0] = (f32x4){0.f, 0.f, 0.f, 0.f};
        s[1] = (f32x4){0.f, 0.f, 0.f, 0.f};
        #pragma unroll
        for (int st = 0; st < 8; ++st) {
            bf16x8 a0 = *(const bf16x8*)&Fq[(size_t)l16 * HCH + st * 32 + quad * 8];
            bf16x8 a1 = *(const bf16x8*)&Fq[(size_t)(16 + l16) * HCH + st * 32 + quad * 8];
            bf16x8 bg = *(const bf16x8*)(Gb + (size_t)st * (NPIX * 32)
                                         + ((((kk + l16) * 32) + quad * 8) ^ gx));
            s[0] = MFMA16(a0, bg, s[0]);
            s[1] = MFMA16(a1, bg, s[1]);
        }

        float p[2][4];
        #pragma unroll
        for (int qs = 0; qs < 2; ++qs)
            #pragma unroll
            for (int r = 0; r < 4; ++r)
                p[qs][r] = exp2f(L2E * s[qs][r]) * linv[qs][r];

        #pragma unroll
        for (int qs = 0; qs < 2; ++qs)
            #pragma unroll
            for (int r = 0; r < 4; ++r)
                Pl[buf][qs * 16 + quad * 4 + r][wave * 16 + l16] = f2bf(p[qs][r]);

        if (ch == 0) {
            float cs = p[0][0] + p[0][1] + p[0][2] + p[0][3]
                     + p[1][0] + p[1][1] + p[1][2] + p[1][3];
            cs += __shfl_xor(cs, 16, 64);
            cs += __shfl_xor(cs, 32, 64);
            if (quad == 0)
                atomicAdd(&attnacc[(size_t)b * NPIX + kk + l16], cs);
        }

        __syncthreads();

        #pragma unroll
        for (int ks = 0; ks < 4; ++ks) {
            bf16x8 pa0 = *(const bf16x8*)&Pl[buf][l16][ks * 32 + quad * 8];
            bf16x8 pa1 = *(const bf16x8*)&Pl[buf][16 + l16][ks * 32 + quad * 8];
            const unsigned short* vs = Vb + ((size_t)(k0 >> 5) + ks) * (CH * 32);
            #pragma unroll
            for (int ct = 0; ct < 2; ++ct) {
                const int el = (((cw + ct * 16 + l16) * 32) + quad * 8) ^ vx;
                bf16x8 vv = *(const bf16x8*)(vs + el);
                O[0][ct] = MFMA16(pa0, vv, O[0][ct]);
                O[1][ct] = MFMA16(pa1, vv, O[1][ct]);
            }
        }
        buf ^= 1;
    }

    #pragma unroll
    for (int qs = 0; qs < 2; ++qs) {
        #pragma unroll
        for (int ct = 0; ct < 2; ++ct) {
            const int c = cw + ct * 16 + l16;
            *(f32x4*)&outres[((size_t)b * CH + c) * NPIX + q0 + qs * 16 + quad * 4] = O[qs][ct];
        }
    }
}

__global__ __launch_bounds__(256) void attn_fin_kernel(
    const float* __restrict__ acc, float* __restrict__ outa)
{
    const int i = blockIdx.x * 256 + threadIdx.x;
    if (i < BATCH * NPIX) outa[i] = acc[i] * (1.0f / (float)NPIX);
}

extern "C" void kernel_launch(void* const* d_in, const int* in_sizes, int n_in,
                              void* d_out, int out_size, void* d_ws, size_t ws_size,
                              hipStream_t stream)
{
    (void)in_sizes; (void)n_in; (void)out_size;
    const float* x  = (const float*)d_in[0];
    const float* Wf = (const float*)d_in[1];
    const float* bf = (const float*)d_in[2];
    const float* Wg = (const float*)d_in[3];
    const float* bg = (const float*)d_in[4];
    const float* Wh = (const float*)d_in[5];
    const float* bh = (const float*)d_in[6];
    float* out = (float*)d_out;

    const size_t P_ELEMS  = (size_t)BATCH * 128 * NPIX * 32;   // 67,108,864
    const size_t XP_ELEMS = (size_t)BATCH * 16 * NPIX * 32;    //  8,388,608
    const size_t F_ELEMS  = (size_t)BATCH * NPIX * HCH;        //  4,194,304
    const size_t V_ELEMS  = (size_t)BATCH * 128 * CH * 32;     //  8,388,608
    const size_t NEED = (P_ELEMS + 2 * F_ELEMS + V_ELEMS) * 2
                      + (size_t)2 * BATCH * NPIX * 4;          // ~167.9 MB

    if (ws_size >= NEED) {
        // ---- materialized-P path. P overlays Xp+Wc (dead before score).
        unsigned short* P  = (unsigned short*)d_ws;
        unsigned short* Xp = P;
        unsigned short* Wc = P + XP_ELEMS;
        unsigned short* F  = P + P_ELEMS;
        unsigned short* G  = F + F_ELEMS;
        unsigned short* V  = G + F_ELEMS;
        float* rowl    = (float*)(V + V_ELEMS);
        float* attnacc = rowl + (size_t)BATCH * NPIX;

        hipMemsetAsync(rowl, 0, (size_t)BATCH * NPIX * sizeof(float), stream);

        convert_w_kernel<<<512, 256, 0, stream>>>(Wf, Wg, Wh, Wc);
        convert_x_kernel<<<dim3(NPIX / 64, 16, BATCH), 256, 0, stream>>>(x, Xp);

        proj_fg_kernel<<<dim3(NPIX / 64, 4, BATCH), 256, 0, stream>>>(Wc, Xp, bf, bg, F, G);
        proj_v_kernel<<<dim3(8, NPIX / 128, BATCH), 256, 0, stream>>>(Wc, Xp, bh, V);

        score_kernel<<<512, 512, 0, stream>>>(F, G, P, rowl);
        pv_kernel<<<512, 512, 0, stream>>>(P, V, rowl, out);
        colsum_kernel<<<512, 256, 0, stream>>>(P, rowl, attnacc);

        attn_fin_kernel<<<BATCH * NPIX / 256, 256, 0, stream>>>(
            attnacc, out + (size_t)BATCH * CH * NPIX);
    } else {
        // ---- fallback: stats+apply (G/V images swizzled; readers XOR).
        unsigned short* Xp = (unsigned short*)d_ws;
        unsigned short* Wc = Xp + XP_ELEMS;
        unsigned short* F  = Wc + (size_t)1024 * CH;
        unsigned short* G  = F + F_ELEMS;
        unsigned short* V  = G + F_ELEMS;
        float* rowl    = (float*)(V + V_ELEMS);
        float* attnacc = rowl + (size_t)BATCH * NPIX;

        hipMemsetAsync(rowl, 0, (size_t)2 * BATCH * NPIX * sizeof(float), stream);

        convert_w_kernel<<<512, 256, 0, stream>>>(Wf, Wg, Wh, Wc);
        convert_x_kernel<<<dim3(NPIX / 64, 16, BATCH), 256, 0, stream>>>(x, Xp);

        proj_fg_kernel<<<dim3(NPIX / 64, 4, BATCH), 256, 0, stream>>>(Wc, Xp, bf, bg, F, G);
        proj_v_kernel<<<dim3(8, NPIX / 128, BATCH), 256, 0, stream>>>(Wc, Xp, bh, V);

        stats_kernel<<<512, 512, 0, stream>>>(F, G, rowl);
        apply_kernel<<<1024, 512, 0, stream>>>(F, G, V, rowl, out, attnacc);

        attn_fin_kernel<<<BATCH * NPIX / 256, 256, 0, stream>>>(
            attnacc, out + (size_t)BATCH * CH * NPIX);
    }
}